// Round 7
// baseline (210.297 us; speedup 1.0000x reference)
//
#include <hip/hip_runtime.h>

typedef short short8 __attribute__((ext_vector_type(8)));
typedef unsigned short ushort8 __attribute__((ext_vector_type(8)));
typedef float f32x4 __attribute__((ext_vector_type(4)));

#define NEG 0.01f

static __device__ __forceinline__ float leaky(float x) { return x >= 0.f ? x : NEG * x; }

static __device__ __forceinline__ unsigned short f2bf(float f) {
    unsigned int u = __float_as_uint(f);
    unsigned int r = (u + 0x7fff + ((u >> 16) & 1)) >> 16;
    return (unsigned short)r;
}

// ---------------- 1. maxpool 2x2 (both tensors), NCHW fp32 ----------------
__global__ __launch_bounds__(256) void pool_kernel(const float* __restrict__ rgb,
                                                   const float* __restrict__ ir,
                                                   float* __restrict__ Pr,
                                                   float* __restrict__ Pi) {
    const float* src = blockIdx.y ? ir : rgb;
    float* dst = blockIdx.y ? Pi : Pr;
    int q = blockIdx.x * 256 + threadIdx.x;   // float4 index, 524288 total
    int ow4 = q & 15;                          // 16 float4 per out row
    int t = q >> 4;
    int oh = t & 63;
    int nc = t >> 6;                           // n*128+c
    const float* ib = src + ((size_t)(nc * 128 + 2 * oh)) * 128 + ow4 * 8;
    float4 a0 = *(const float4*)(ib);
    float4 a1 = *(const float4*)(ib + 4);
    float4 b0 = *(const float4*)(ib + 128);
    float4 b1 = *(const float4*)(ib + 132);
    float4 o;
    o.x = fmaxf(fmaxf(a0.x, a0.y), fmaxf(b0.x, b0.y));
    o.y = fmaxf(fmaxf(a0.z, a0.w), fmaxf(b0.z, b0.w));
    o.z = fmaxf(fmaxf(a1.x, a1.y), fmaxf(b1.x, b1.y));
    o.w = fmaxf(fmaxf(a1.z, a1.w), fmaxf(b1.z, b1.w));
    *(float4*)(dst + (size_t)q * 4) = o;
}

// ---- 2. transpose to (n,hw,c), l2-normalize -> bf16; batch0 fp32 rows ----
__global__ __launch_bounds__(256) void normT_kernel(const float* __restrict__ Pr,
                                                    const float* __restrict__ Pi,
                                                    float* __restrict__ Pt0r,
                                                    float* __restrict__ Pt0i,
                                                    unsigned short* __restrict__ xnr,
                                                    unsigned short* __restrict__ xni) {
    const float* P = blockIdx.z ? Pi : Pr;
    float* Pt0 = blockIdx.z ? Pt0i : Pt0r;
    unsigned short* xn = blockIdx.z ? xni : xnr;
    int n = blockIdx.y;
    int hw0 = blockIdx.x * 32;
    __shared__ float tile[32][129];
    __shared__ float psum[32][8];
    __shared__ float invn[32];
    int hwl = threadIdx.x & 31;
    int cg = threadIdx.x >> 5;
    float ssq = 0.f;
#pragma unroll
    for (int ii = 0; ii < 16; ++ii) {
        int c = cg * 16 + ii;
        float v = P[((size_t)(n * 128 + c)) * 4096 + hw0 + hwl];
        tile[hwl][c] = v;
        ssq += v * v;
    }
    psum[hwl][cg] = ssq;
    __syncthreads();
    if (threadIdx.x < 32) {
        float s = 0.f;
#pragma unroll
        for (int g = 0; g < 8; ++g) s += psum[threadIdx.x][g];
        invn[threadIdx.x] = 1.0f / fmaxf(sqrtf(s), 1e-12f);
    }
    __syncthreads();
    int c = threadIdx.x & 127;
    int rh = threadIdx.x >> 7;
#pragma unroll
    for (int rr = 0; rr < 16; ++rr) {
        int r = rh * 16 + rr;
        float v = tile[r][c];
        xn[((size_t)n * 4096 + hw0 + r) * 128 + c] = f2bf(v * invn[r]);
        if (n == 0) Pt0[(size_t)(hw0 + r) * 128 + c] = v;
    }
}

// ------ 3. fused gram (bf16 MFMA) + sorted top-16, candidate-quartered ----
// grid: (64 row-blocks of 64 queries, 4 cand-quarters, 8 nz); 256 thr.
// Single-buffer LDS (16.6 KB -> 8 blocks/CU schedulable), reg prefetch,
// 2 barriers/tile. Per lane: 16 scores/tile packed (positive-biased float
// bits | 12-bit idx), Batcher sort-16 + bitonic merge into sorted running
// top-16; 4 kg-runs merged in-kernel; sorted top-16 per (query,quarter) out.
__global__ __launch_bounds__(256, 6) void knn_kernel(const unsigned short* __restrict__ xnr,
                                                     const unsigned short* __restrict__ xni,
                                                     unsigned* __restrict__ Cand) {
    __shared__ __align__(16) char smem[16640];   // 16KB tile buf / 64x65 u32 merge buf
    const int nz = blockIdx.z;
    const int n = nz >> 1;
    const unsigned short* xn = (nz & 1) ? xni : xnr;
    const int quarter = blockIdx.y;
    const int r0 = blockIdx.x * 64;
    const int tid = threadIdx.x;
    const int wave = tid >> 6, lane = tid & 63;
    const int frow = lane & 15, kg = lane >> 4;
    const int aswz = (frow & 7) << 4;
    const int kg16 = kg * 16;
    const int cand0 = quarter * 1024;

    // B-fragments: this wave's 16 query rows, loaded once
    short8 bq[4];
    {
        const unsigned short* qsrc = xn + ((size_t)n * 4096 + r0 + wave * 16 + frow) * 128;
#pragma unroll
        for (int kt = 0; kt < 4; ++kt)
            bq[kt] = *(const short8*)(qsrc + kt * 32 + kg * 8);
    }

    // stage tile 0 (XOR-swizzled rows of 256B)
    {
        const unsigned short* src = xn + ((size_t)n * 4096 + cand0) * 128;
#pragma unroll
        for (int it = 0; it < 4; ++it) {
            int idx = it * 256 + tid;
            int r = idx >> 4, ch = idx & 15;
            short8 v = *(const short8*)(src + r * 128 + ch * 8);
            *(short8*)(smem + r * 256 + ((ch * 16) ^ ((r & 7) << 4))) = v;
        }
    }
    __syncthreads();

    unsigned val[16];   // running top-16, sorted descending
#pragma unroll
    for (int s = 0; s < 16; ++s) val[s] = 0u;

    for (int t = 0; t < 16; ++t) {
        // prefetch next candidate tile into regs
        short8 g[4];
        if (t < 15) {
            const unsigned short* src = xn + ((size_t)n * 4096 + cand0 + (t + 1) * 64) * 128;
#pragma unroll
            for (int it = 0; it < 4; ++it) {
                int idx = it * 256 + tid;
                g[it] = *(const short8*)(src + (idx >> 4) * 128 + (idx & 15) * 8);
            }
        }
        f32x4 acc0 = {2.f, 2.f, 2.f, 2.f}, acc1 = {2.f, 2.f, 2.f, 2.f};
        f32x4 acc2 = {2.f, 2.f, 2.f, 2.f}, acc3 = {2.f, 2.f, 2.f, 2.f};
#pragma unroll
        for (int kt = 0; kt < 4; ++kt) {
            int ko = (kt * 64 + kg16) ^ aswz;
            short8 b = bq[kt];
            short8 a0 = *(const short8*)(smem + (frow)*256 + ko);
            short8 a1 = *(const short8*)(smem + (16 + frow) * 256 + ko);
            short8 a2 = *(const short8*)(smem + (32 + frow) * 256 + ko);
            short8 a3 = *(const short8*)(smem + (48 + frow) * 256 + ko);
            acc0 = __builtin_amdgcn_mfma_f32_16x16x32_bf16(a0, b, acc0, 0, 0, 0);
            acc1 = __builtin_amdgcn_mfma_f32_16x16x32_bf16(a1, b, acc1, 0, 0, 0);
            acc2 = __builtin_amdgcn_mfma_f32_16x16x32_bf16(a2, b, acc2, 0, 0, 0);
            acc3 = __builtin_amdgcn_mfma_f32_16x16x32_bf16(a3, b, acc3, 0, 0, 0);
        }
        // pack: positive-biased score bits (top 20) | candidate idx (12 bits)
        unsigned pk[16];
        const int cb = cand0 + t * 64 + kg * 4;
#define PACK(AC, A_)                                                                        \
    {                                                                                       \
        _Pragma("unroll") for (int j = 0; j < 4; ++j) {                                     \
            pk[A_ * 4 + j] = (__float_as_uint(AC[j]) & 0xFFFFF000u) |                       \
                             (unsigned)(cb + A_ * 16 + j);                                  \
        }                                                                                   \
    }
        PACK(acc0, 0) PACK(acc1, 1) PACK(acc2, 2) PACK(acc3, 3)
#undef PACK

        // Batcher odd-even mergesort, 16 elements, descending (63 CE)
#define CE(i, j)                                          \
    {                                                     \
        unsigned mx = max(pk[i], pk[j]);                  \
        unsigned mn = min(pk[i], pk[j]);                  \
        pk[i] = mx; pk[j] = mn;                           \
    }
        CE(0,1) CE(2,3) CE(4,5) CE(6,7) CE(8,9) CE(10,11) CE(12,13) CE(14,15)
        CE(0,2) CE(1,3) CE(4,6) CE(5,7) CE(8,10) CE(9,11) CE(12,14) CE(13,15)
        CE(1,2) CE(5,6) CE(9,10) CE(13,14)
        CE(0,4) CE(1,5) CE(2,6) CE(3,7) CE(8,12) CE(9,13) CE(10,14) CE(11,15)
        CE(2,4) CE(3,5) CE(10,12) CE(11,13)
        CE(1,2) CE(3,4) CE(5,6) CE(9,10) CE(11,12) CE(13,14)
        CE(0,8) CE(1,9) CE(2,10) CE(3,11) CE(4,12) CE(5,13) CE(6,14) CE(7,15)
        CE(4,8) CE(5,9) CE(6,10) CE(7,11)
        CE(2,4) CE(3,5) CE(6,8) CE(7,9) CE(10,12) CE(11,13)
        CE(1,2) CE(3,4) CE(5,6) CE(7,8) CE(9,10) CE(11,12) CE(13,14)
#undef CE

        // half-cleaner: top-16 of merge(val desc, pk desc) as bitonic seq
#pragma unroll
        for (int i = 0; i < 16; ++i) val[i] = max(val[i], pk[15 - i]);
        // bitonic merge -> descending sorted
#define CEV(i, j)                                         \
    {                                                     \
        unsigned mx = max(val[i], val[j]);                \
        unsigned mn = min(val[i], val[j]);                \
        val[i] = mx; val[j] = mn;                         \
    }
        CEV(0,8) CEV(1,9) CEV(2,10) CEV(3,11) CEV(4,12) CEV(5,13) CEV(6,14) CEV(7,15)
        CEV(0,4) CEV(1,5) CEV(2,6) CEV(3,7) CEV(8,12) CEV(9,13) CEV(10,14) CEV(11,15)
        CEV(0,2) CEV(1,3) CEV(4,6) CEV(5,7) CEV(8,10) CEV(9,11) CEV(12,14) CEV(13,15)
        CEV(0,1) CEV(2,3) CEV(4,5) CEV(6,7) CEV(8,9) CEV(10,11) CEV(12,13) CEV(14,15)
#undef CEV

        if (t < 15) {
            __syncthreads();   // all waves done reading tile t
#pragma unroll
            for (int it = 0; it < 4; ++it) {
                int idx = it * 256 + tid;
                int r = idx >> 4, ch = idx & 15;
                *(short8*)(smem + r * 256 + ((ch * 16) ^ ((r & 7) << 4))) = g[it];
            }
            __syncthreads();   // tile t+1 visible
        }
    }

    // 4 sorted kg-runs per query -> 4-way merge -> sorted top-16 packed out
    __syncthreads();   // done reading tile buffer; reuse as merge buffer
    {
        unsigned* mbuf = (unsigned*)smem;
        int query = wave * 16 + frow;
#pragma unroll
        for (int s = 0; s < 16; ++s) mbuf[query * 65 + kg16 + s] = val[s];
        __syncthreads();
        if (tid < 64) {
            unsigned* outp = Cand + (((size_t)nz * 4096 + r0 + tid) * 4 + quarter) * 16;
            const unsigned* row = mbuf + tid * 65;
            int h0 = 0, h1 = 0, h2 = 0, h3 = 0;
#pragma unroll 1
            for (int kk = 0; kk < 16; ++kk) {
                unsigned c0 = row[h0], c1 = row[16 + h1], c2 = row[32 + h2], c3 = row[48 + h3];
                unsigned mm = max(max(c0, c1), max(c2, c3));
                outp[kk] = mm;
                h0 += (c0 == mm); h1 += (c1 == mm); h2 += (c2 == mm); h3 += (c3 == mm);
            }
        }
    }
}

// ---- 3b. cross-quarter merge: 4 sorted 16-runs -> final top-16 indices ---
__global__ __launch_bounds__(256) void kmerge_kernel(const unsigned* __restrict__ Cand,
                                                     int* __restrict__ knnr,
                                                     int* __restrict__ knni) {
    int g = blockIdx.x * 256 + threadIdx.x;   // 32768 = nz*4096 + q
    int nz = g >> 12, q = g & 4095;
    int n = nz >> 1;
    int* knn = (nz & 1) ? knni : knnr;
    const unsigned* p = Cand + (size_t)g * 64;
    int* outp = knn + ((size_t)n * 4096 + q) * 16;
    int h0 = 0, h1 = 0, h2 = 0, h3 = 0;
#pragma unroll
    for (int kk = 0; kk < 16; ++kk) {
        unsigned c0 = p[h0], c1 = p[16 + h1], c2 = p[32 + h2], c3 = p[48 + h3];
        unsigned mm = max(max(c0, c1), max(c2, c3));
        outp[kk] = (int)(mm & 0xFFFu);
        h0 += (c0 == mm); h1 += (c1 == mm); h2 += (c2 == mm); h3 += (c3 == mm);
    }
}

// --- 4. fused bf16 node tables with bias folded in -----------------------
// ABa[j] = [ A1'=hr@(W1+W2)+br | B2=hr@V2 ]   (indexed by rgb-knn a)
// ABb[j] = [ A2 =hi@W2         | B1'=hi@(V1+V2)+bi ]   (indexed by ir-knn b)
__global__ __launch_bounds__(256) void table_kernel(const float* __restrict__ Pt0r,
                                                    const float* __restrict__ Pt0i,
                                                    const float* __restrict__ Wr,
                                                    const float* __restrict__ Wi,
                                                    const float* __restrict__ b_rgb,
                                                    const float* __restrict__ b_ir,
                                                    unsigned short* __restrict__ ABa,
                                                    unsigned short* __restrict__ ABb) {
    int tbl = blockIdx.y;
    const float* X = (tbl == 0 || tbl == 3) ? Pt0r : Pt0i;
    const float* W = (tbl <= 1) ? Wr : Wi;
    bool comb = (tbl == 0 || tbl == 2);
    unsigned short* out = (tbl == 0 || tbl == 3) ? ABa : ABb;
    int off = (tbl <= 1) ? 0 : 128;
    __shared__ float Xl[32][128];
    int j0 = blockIdx.x * 32;
    for (int q = threadIdx.x; q < 32 * 128; q += 256)
        Xl[q >> 7][q & 127] = X[(size_t)(j0 + (q >> 7)) * 128 + (q & 127)];
    __syncthreads();
    int c = threadIdx.x & 127;
    int jh = threadIdx.x >> 7;
    float bv = (tbl == 0) ? b_rgb[c] : (tbl == 2) ? b_ir[c] : 0.f;
    float acc[16];
#pragma unroll
    for (int s = 0; s < 16; ++s) acc[s] = bv;
    for (int d4 = 0; d4 < 32; ++d4) {
        float w[4];
#pragma unroll
        for (int u = 0; u < 4; ++u) {
            int d = d4 * 4 + u;
            w[u] = W[(size_t)(d + 128) * 128 + c];
            if (comb) w[u] += W[(size_t)d * 128 + c];
        }
#pragma unroll
        for (int jj = 0; jj < 16; ++jj) {
            const float4 xv = *(const float4*)&Xl[jh * 16 + jj][d4 * 4];
            acc[jj] = fmaf(xv.x, w[0], fmaf(xv.y, w[1], fmaf(xv.z, w[2], fmaf(xv.w, w[3], acc[jj]))));
        }
    }
#pragma unroll
    for (int jj = 0; jj < 16; ++jj)
        out[(size_t)(j0 + jh * 16 + jj) * 256 + off + c] = f2bf(acc[jj]);
}

// ------ 5. pair accumulation: bf16 fused rows, 2 gathers per pair ---------
__global__ __launch_bounds__(256) void pairsum_kernel(const int* __restrict__ knnr,
                                                      const int* __restrict__ knni,
                                                      const unsigned short* __restrict__ ABa,
                                                      const unsigned short* __restrict__ ABb,
                                                      float* __restrict__ Spart) {
    __shared__ int ia[512], ib[512];
    __shared__ float red[8][256];
    int chunk = blockIdx.x, n = blockIdx.y;
    int i0 = chunk * 32;
    for (int q = threadIdx.x; q < 512; q += 256) {
        int i = i0 + (q >> 4), kk = q & 15;
        ia[q] = knnr[((size_t)n * 4096 + i) * 16 + kk];
        ib[q] = knni[((size_t)n * 4096 + i) * 16 + kk];
    }
    __syncthreads();
    int c4 = threadIdx.x & 31, hw = threadIdx.x >> 5;   // 8 half-waves
    // lanes 0-15: rgb part  leaky(A1'[a]-A2[b]); lanes 16-31: ir part leaky(B1'[b]-B2[a])
    float s = (c4 < 16) ? 1.f : -1.f;
    float acc[8];
#pragma unroll
    for (int j = 0; j < 8; ++j) acc[j] = 0.f;
#pragma unroll 4
    for (int q = hw; q < 512; q += 8) {
        int a = ia[q], b = ib[q];
        ushort8 ua = *(const ushort8*)(ABa + (size_t)a * 256 + c4 * 8);
        ushort8 ub = *(const ushort8*)(ABb + (size_t)b * 256 + c4 * 8);
#pragma unroll
        for (int j = 0; j < 8; ++j) {
            float av = __uint_as_float((unsigned)ua[j] << 16);
            float bv = __uint_as_float((unsigned)ub[j] << 16);
            float x = s * (av - bv);
            acc[j] += (x >= 0.f) ? x : NEG * x;
        }
    }
    *(float4*)&red[hw][c4 * 8] = *(float4*)&acc[0];
    *(float4*)&red[hw][c4 * 8 + 4] = *(float4*)&acc[4];
    __syncthreads();
    float ssum = 0.f;
#pragma unroll
    for (int p = 0; p < 8; ++p) ssum += red[p][threadIdx.x];
    Spart[((size_t)n * 128 + chunk) * 256 + threadIdx.x] = ssum;
}

// ---------- 6a. partial reduce of Spart: 128 partials -> 16 ----------------
__global__ __launch_bounds__(256) void reduce_kernel(const float* __restrict__ Spart,
                                                     float* __restrict__ Spart2) {
    int seg = blockIdx.x, n = blockIdx.y;
    int d = threadIdx.x;
    float s = 0.f;
#pragma unroll
    for (int j = 0; j < 8; ++j)
        s += Spart[((size_t)n * 128 + seg * 8 + j) * 256 + d];
    Spart2[((size_t)n * 16 + seg) * 256 + d] = s;
}

// --------------------- 6b. SE gate (tiny, 1 block/batch) ------------------
__global__ __launch_bounds__(256) void gate_kernel(const float* __restrict__ Spart2,
                                                   const float* __restrict__ se_w1,
                                                   const float* __restrict__ se_b1,
                                                   const float* __restrict__ se_w2,
                                                   const float* __restrict__ se_b2,
                                                   float* __restrict__ gate) {
    int n = blockIdx.x;
    __shared__ float m[256];
    __shared__ float hid[8];
    int d = threadIdx.x;
    float s = 0.f;
#pragma unroll
    for (int seg = 0; seg < 16; ++seg)
        s += Spart2[((size_t)n * 16 + seg) * 256 + d];
    m[d] = s * (1.0f / 65536.0f);
    __syncthreads();
    if (threadIdx.x < 8) {
        float h = se_b1[threadIdx.x];
        for (int dd = 0; dd < 256; ++dd) h += m[dd] * se_w1[dd * 8 + threadIdx.x];
        hid[threadIdx.x] = leaky(h);
    }
    __syncthreads();
    if (threadIdx.x < 128) {
        float z = se_b2[threadIdx.x];
#pragma unroll
        for (int j = 0; j < 8; ++j) z += hid[j] * se_w2[j * 128 + threadIdx.x];
        gate[n * 128 + threadIdx.x] = 1.0f / (1.0f + expf(-z));
    }
}

// -------------------- 7. blend + relu, NCHW output ------------------------
__global__ __launch_bounds__(256) void out_kernel(const float* __restrict__ Pr,
                                                  const float* __restrict__ Pi,
                                                  const float* __restrict__ gate,
                                                  const float* __restrict__ g1p,
                                                  const float* __restrict__ g2p,
                                                  float* __restrict__ out) {
    int q = blockIdx.x * 256 + threadIdx.x;  // float4 idx, 524288 total
    int nc = q >> 10;
    float g = gate[nc];
    float gr = g1p[0] * g, gi = g2p[0] * (1.f - g);
    float4 r = *(const float4*)(Pr + (size_t)q * 4);
    float4 i = *(const float4*)(Pi + (size_t)q * 4);
    float4 o;
    o.x = fmaxf(gr * r.x + gi * i.x, 0.f);
    o.y = fmaxf(gr * r.y + gi * i.y, 0.f);
    o.z = fmaxf(gr * r.z + gi * i.z, 0.f);
    o.w = fmaxf(gr * r.w + gi * i.w, 0.f);
    *(float4*)(out + (size_t)q * 4) = o;
}

extern "C" void kernel_launch(void* const* d_in, const int* in_sizes, int n_in,
                              void* d_out, int out_size, void* d_ws, size_t ws_size,
                              hipStream_t stream) {
    const float* rgb = (const float*)d_in[0];
    const float* ir = (const float*)d_in[1];
    const float* Wr = (const float*)d_in[2];
    const float* br = (const float*)d_in[3];
    const float* Wi = (const float*)d_in[4];
    const float* bi = (const float*)d_in[5];
    const float* sw1 = (const float*)d_in[6];
    const float* sb1 = (const float*)d_in[7];
    const float* sw2 = (const float*)d_in[8];
    const float* sb2 = (const float*)d_in[9];
    const float* g1 = (const float*)d_in[10];
    const float* g2 = (const float*)d_in[11];
    float* out = (float*)d_out;

    char* ws = (char*)d_ws;
    float* Pr = (float*)ws;                     ws += (size_t)8 << 20;
    float* Pi = (float*)ws;                     ws += (size_t)8 << 20;
    unsigned short* xnr = (unsigned short*)ws;  ws += (size_t)4 << 20;
    unsigned short* xni = (unsigned short*)ws;  ws += (size_t)4 << 20;
    float* Pt0r = (float*)ws;                   ws += (size_t)2 << 20;
    float* Pt0i = (float*)ws;                   ws += (size_t)2 << 20;
    int* knnr = (int*)ws;                       ws += (size_t)1 << 20;
    int* knni = (int*)ws;                       ws += (size_t)1 << 20;
    unsigned* Cand = (unsigned*)ws;             ws += (size_t)8 << 20;
    unsigned short* ABa = (unsigned short*)ws;  ws += (size_t)2 << 20;
    unsigned short* ABb = (unsigned short*)ws;  ws += (size_t)2 << 20;
    float* Spart = (float*)ws;                  ws += (size_t)512 << 10;
    float* Spart2 = (float*)ws;                 ws += (size_t)64 << 10;
    float* gate = (float*)ws;                   ws += 4096;

    pool_kernel<<<dim3(2048, 2), 256, 0, stream>>>(rgb, ir, Pr, Pi);
    normT_kernel<<<dim3(128, 4, 2), 256, 0, stream>>>(Pr, Pi, Pt0r, Pt0i, xnr, xni);
    knn_kernel<<<dim3(64, 4, 8), 256, 0, stream>>>(xnr, xni, Cand);
    kmerge_kernel<<<128, 256, 0, stream>>>(Cand, knnr, knni);
    table_kernel<<<dim3(128, 4), 256, 0, stream>>>(Pt0r, Pt0i, Wr, Wi, br, bi, ABa, ABb);
    pairsum_kernel<<<dim3(128, 4), 256, 0, stream>>>(knnr, knni, ABa, ABb, Spart);
    reduce_kernel<<<dim3(16, 4), 256, 0, stream>>>(Spart, Spart2);
    gate_kernel<<<4, 256, 0, stream>>>(Spart2, sw1, sb1, sw2, sb2, gate);
    out_kernel<<<2048, 256, 0, stream>>>(Pr, Pi, gate, g1, g2, out);
}

// Round 8
// 190.899 us; speedup vs baseline: 1.1016x; 1.1016x over previous
//
#include <hip/hip_runtime.h>

typedef short short8 __attribute__((ext_vector_type(8)));
typedef unsigned short ushort8 __attribute__((ext_vector_type(8)));
typedef float f32x4 __attribute__((ext_vector_type(4)));

#define NEG 0.01f

static __device__ __forceinline__ float leaky(float x) { return x >= 0.f ? x : NEG * x; }

static __device__ __forceinline__ unsigned short f2bf(float f) {
    unsigned int u = __float_as_uint(f);
    unsigned int r = (u + 0x7fff + ((u >> 16) & 1)) >> 16;
    return (unsigned short)r;
}

// ---------------- 1. maxpool 2x2 (both tensors), NCHW fp32 ----------------
__global__ __launch_bounds__(256) void pool_kernel(const float* __restrict__ rgb,
                                                   const float* __restrict__ ir,
                                                   float* __restrict__ Pr,
                                                   float* __restrict__ Pi) {
    const float* src = blockIdx.y ? ir : rgb;
    float* dst = blockIdx.y ? Pi : Pr;
    int q = blockIdx.x * 256 + threadIdx.x;   // float4 index, 524288 total
    int ow4 = q & 15;                          // 16 float4 per out row
    int t = q >> 4;
    int oh = t & 63;
    int nc = t >> 6;                           // n*128+c
    const float* ib = src + ((size_t)(nc * 128 + 2 * oh)) * 128 + ow4 * 8;
    float4 a0 = *(const float4*)(ib);
    float4 a1 = *(const float4*)(ib + 4);
    float4 b0 = *(const float4*)(ib + 128);
    float4 b1 = *(const float4*)(ib + 132);
    float4 o;
    o.x = fmaxf(fmaxf(a0.x, a0.y), fmaxf(b0.x, b0.y));
    o.y = fmaxf(fmaxf(a0.z, a0.w), fmaxf(b0.z, b0.w));
    o.z = fmaxf(fmaxf(a1.x, a1.y), fmaxf(b1.x, b1.y));
    o.w = fmaxf(fmaxf(a1.z, a1.w), fmaxf(b1.z, b1.w));
    *(float4*)(dst + (size_t)q * 4) = o;
}

// ---- 2. transpose to (n,hw,c), l2-normalize -> bf16; batch0 fp32 rows ----
__global__ __launch_bounds__(256) void normT_kernel(const float* __restrict__ Pr,
                                                    const float* __restrict__ Pi,
                                                    float* __restrict__ Pt0r,
                                                    float* __restrict__ Pt0i,
                                                    unsigned short* __restrict__ xnr,
                                                    unsigned short* __restrict__ xni) {
    const float* P = blockIdx.z ? Pi : Pr;
    float* Pt0 = blockIdx.z ? Pt0i : Pt0r;
    unsigned short* xn = blockIdx.z ? xni : xnr;
    int n = blockIdx.y;
    int hw0 = blockIdx.x * 32;
    __shared__ float tile[32][129];
    __shared__ float psum[32][8];
    __shared__ float invn[32];
    int hwl = threadIdx.x & 31;
    int cg = threadIdx.x >> 5;
    float ssq = 0.f;
#pragma unroll
    for (int ii = 0; ii < 16; ++ii) {
        int c = cg * 16 + ii;
        float v = P[((size_t)(n * 128 + c)) * 4096 + hw0 + hwl];
        tile[hwl][c] = v;
        ssq += v * v;
    }
    psum[hwl][cg] = ssq;
    __syncthreads();
    if (threadIdx.x < 32) {
        float s = 0.f;
#pragma unroll
        for (int g = 0; g < 8; ++g) s += psum[threadIdx.x][g];
        invn[threadIdx.x] = 1.0f / fmaxf(sqrtf(s), 1e-12f);
    }
    __syncthreads();
    int c = threadIdx.x & 127;
    int rh = threadIdx.x >> 7;
#pragma unroll
    for (int rr = 0; rr < 16; ++rr) {
        int r = rh * 16 + rr;
        float v = tile[r][c];
        xn[((size_t)n * 4096 + hw0 + r) * 128 + c] = f2bf(v * invn[r]);
        if (n == 0) Pt0[(size_t)(hw0 + r) * 128 + c] = v;
    }
}

// ------ 3. fused gram (bf16 MFMA) + sorted top-16, candidate-quartered ----
// grid: (64 row-blocks of 64 queries, 4 cand-quarters, 8 nz); 256 thr.
// Double-buffered LDS with reg prefetch, 1 barrier/tile. 4-bit XOR swizzle
// slot = ch ^ (r&15): read slot = (kt*4+kg) ^ frow -> even 4 lanes/slot
// (b128-optimal; the old 3-bit swizzle bunched 8 lanes on 8 slots).
// Per lane: 16 scores/tile packed (positive-biased float bits | 12-bit idx),
// Batcher sort-16 + bitonic merge into sorted running top-16; 4 kg-runs
// merged in-kernel; sorted top-16 per (query,quarter) out to Cand.
__global__ __launch_bounds__(256, 4) void knn_kernel(const unsigned short* __restrict__ xnr,
                                                     const unsigned short* __restrict__ xni,
                                                     unsigned* __restrict__ Cand) {
    __shared__ __align__(16) char smem[32768];   // 2 x 16KB tiles; merge buf overlay
    const int nz = blockIdx.z;
    const int n = nz >> 1;
    const unsigned short* xn = (nz & 1) ? xni : xnr;
    const int quarter = blockIdx.y;
    const int r0 = blockIdx.x * 64;
    const int tid = threadIdx.x;
    const int wave = tid >> 6, lane = tid & 63;
    const int frow = lane & 15, kg = lane >> 4;
    const int kg16 = kg * 16;
    const int cand0 = quarter * 1024;

    // B-fragments: this wave's 16 query rows, loaded once
    short8 bq[4];
    {
        const unsigned short* qsrc = xn + ((size_t)n * 4096 + r0 + wave * 16 + frow) * 128;
#pragma unroll
        for (int kt = 0; kt < 4; ++kt)
            bq[kt] = *(const short8*)(qsrc + kt * 32 + kg * 8);
    }

    // stage tile 0 into buf0 (4-bit XOR swizzle)
    {
        const unsigned short* src = xn + ((size_t)n * 4096 + cand0) * 128;
#pragma unroll
        for (int it = 0; it < 4; ++it) {
            int idx = it * 256 + tid;
            int r = idx >> 4, ch = idx & 15;
            short8 v = *(const short8*)(src + r * 128 + ch * 8);
            *(short8*)(smem + r * 256 + ((ch ^ (r & 15)) << 4)) = v;
        }
    }
    __syncthreads();

    unsigned val[16];   // running top-16, sorted descending
#pragma unroll
    for (int s = 0; s < 16; ++s) val[s] = 0u;

    for (int t = 0; t < 16; ++t) {
        // prefetch next candidate tile into regs
        short8 g[4];
        if (t < 15) {
            const unsigned short* src = xn + ((size_t)n * 4096 + cand0 + (t + 1) * 64) * 128;
#pragma unroll
            for (int it = 0; it < 4; ++it) {
                int idx = it * 256 + tid;
                g[it] = *(const short8*)(src + (idx >> 4) * 128 + (idx & 15) * 8);
            }
        }
        const char* bc = smem + ((t & 1) ? 16384 : 0);
        f32x4 acc0 = {2.f, 2.f, 2.f, 2.f}, acc1 = {2.f, 2.f, 2.f, 2.f};
        f32x4 acc2 = {2.f, 2.f, 2.f, 2.f}, acc3 = {2.f, 2.f, 2.f, 2.f};
#pragma unroll
        for (int kt = 0; kt < 4; ++kt) {
            int ko = (kt * 64 + kg16) ^ (frow << 4);
            short8 b = bq[kt];
            short8 a0 = *(const short8*)(bc + (frow)*256 + ko);
            short8 a1 = *(const short8*)(bc + (16 + frow) * 256 + ko);
            short8 a2 = *(const short8*)(bc + (32 + frow) * 256 + ko);
            short8 a3 = *(const short8*)(bc + (48 + frow) * 256 + ko);
            acc0 = __builtin_amdgcn_mfma_f32_16x16x32_bf16(a0, b, acc0, 0, 0, 0);
            acc1 = __builtin_amdgcn_mfma_f32_16x16x32_bf16(a1, b, acc1, 0, 0, 0);
            acc2 = __builtin_amdgcn_mfma_f32_16x16x32_bf16(a2, b, acc2, 0, 0, 0);
            acc3 = __builtin_amdgcn_mfma_f32_16x16x32_bf16(a3, b, acc3, 0, 0, 0);
        }
        // pack: positive-biased score bits (top 20) | candidate idx (12 bits)
        unsigned pk[16];
        const int cb = cand0 + t * 64 + kg * 4;
#define PACK(AC, A_)                                                                        \
    {                                                                                       \
        _Pragma("unroll") for (int j = 0; j < 4; ++j) {                                     \
            pk[A_ * 4 + j] = (__float_as_uint(AC[j]) & 0xFFFFF000u) |                       \
                             (unsigned)(cb + A_ * 16 + j);                                  \
        }                                                                                   \
    }
        PACK(acc0, 0) PACK(acc1, 1) PACK(acc2, 2) PACK(acc3, 3)
#undef PACK

        // Batcher odd-even mergesort, 16 elements, descending (63 CE)
#define CE(i, j)                                          \
    {                                                     \
        unsigned mx = max(pk[i], pk[j]);                  \
        unsigned mn = min(pk[i], pk[j]);                  \
        pk[i] = mx; pk[j] = mn;                           \
    }
        CE(0,1) CE(2,3) CE(4,5) CE(6,7) CE(8,9) CE(10,11) CE(12,13) CE(14,15)
        CE(0,2) CE(1,3) CE(4,6) CE(5,7) CE(8,10) CE(9,11) CE(12,14) CE(13,15)
        CE(1,2) CE(5,6) CE(9,10) CE(13,14)
        CE(0,4) CE(1,5) CE(2,6) CE(3,7) CE(8,12) CE(9,13) CE(10,14) CE(11,15)
        CE(2,4) CE(3,5) CE(10,12) CE(11,13)
        CE(1,2) CE(3,4) CE(5,6) CE(9,10) CE(11,12) CE(13,14)
        CE(0,8) CE(1,9) CE(2,10) CE(3,11) CE(4,12) CE(5,13) CE(6,14) CE(7,15)
        CE(4,8) CE(5,9) CE(6,10) CE(7,11)
        CE(2,4) CE(3,5) CE(6,8) CE(7,9) CE(10,12) CE(11,13)
        CE(1,2) CE(3,4) CE(5,6) CE(7,8) CE(9,10) CE(11,12) CE(13,14)
#undef CE

        // half-cleaner: top-16 of merge(val desc, pk desc) as bitonic seq
#pragma unroll
        for (int i = 0; i < 16; ++i) val[i] = max(val[i], pk[15 - i]);
        // bitonic merge -> descending sorted
#define CEV(i, j)                                         \
    {                                                     \
        unsigned mx = max(val[i], val[j]);                \
        unsigned mn = min(val[i], val[j]);                \
        val[i] = mx; val[j] = mn;                         \
    }
        CEV(0,8) CEV(1,9) CEV(2,10) CEV(3,11) CEV(4,12) CEV(5,13) CEV(6,14) CEV(7,15)
        CEV(0,4) CEV(1,5) CEV(2,6) CEV(3,7) CEV(8,12) CEV(9,13) CEV(10,14) CEV(11,15)
        CEV(0,2) CEV(1,3) CEV(4,6) CEV(5,7) CEV(8,10) CEV(9,11) CEV(12,14) CEV(13,15)
        CEV(0,1) CEV(2,3) CEV(4,5) CEV(6,7) CEV(8,9) CEV(10,11) CEV(12,13) CEV(14,15)
#undef CEV

        // write prefetched tile t+1 into the other buffer (safe: the barrier
        // ending iter t-1 guaranteed all waves finished reading it)
        if (t < 15) {
            char* bn = smem + ((t & 1) ? 0 : 16384);
#pragma unroll
            for (int it = 0; it < 4; ++it) {
                int idx = it * 256 + tid;
                int r = idx >> 4, ch = idx & 15;
                *(short8*)(bn + r * 256 + ((ch ^ (r & 15)) << 4)) = g[it];
            }
        }
        __syncthreads();
    }

    // 4 sorted kg-runs per query -> 4-way merge -> sorted top-16 packed out
    {
        unsigned* mbuf = (unsigned*)smem;
        int query = wave * 16 + frow;
#pragma unroll
        for (int s = 0; s < 16; ++s) mbuf[query * 65 + kg16 + s] = val[s];
        __syncthreads();
        if (tid < 64) {
            unsigned* outp = Cand + (((size_t)nz * 4096 + r0 + tid) * 4 + quarter) * 16;
            const unsigned* row = mbuf + tid * 65;
            int h0 = 0, h1 = 0, h2 = 0, h3 = 0;
#pragma unroll 1
            for (int kk = 0; kk < 16; ++kk) {
                unsigned c0 = row[h0], c1 = row[16 + h1], c2 = row[32 + h2], c3 = row[48 + h3];
                unsigned mm = max(max(c0, c1), max(c2, c3));
                outp[kk] = mm;
                h0 += (c0 == mm); h1 += (c1 == mm); h2 += (c2 == mm); h3 += (c3 == mm);
            }
        }
    }
}

// --- 4. fused bf16 node tables with bias folded in -----------------------
// ABa[j] = [ A1'=hr@(W1+W2)+br | B2=hr@V2 ]   (indexed by rgb-knn a)
// ABb[j] = [ A2 =hi@W2         | B1'=hi@(V1+V2)+bi ]   (indexed by ir-knn b)
__global__ __launch_bounds__(256) void table_kernel(const float* __restrict__ Pt0r,
                                                    const float* __restrict__ Pt0i,
                                                    const float* __restrict__ Wr,
                                                    const float* __restrict__ Wi,
                                                    const float* __restrict__ b_rgb,
                                                    const float* __restrict__ b_ir,
                                                    unsigned short* __restrict__ ABa,
                                                    unsigned short* __restrict__ ABb) {
    int tbl = blockIdx.y;
    const float* X = (tbl == 0 || tbl == 3) ? Pt0r : Pt0i;
    const float* W = (tbl <= 1) ? Wr : Wi;
    bool comb = (tbl == 0 || tbl == 2);
    unsigned short* out = (tbl == 0 || tbl == 3) ? ABa : ABb;
    int off = (tbl <= 1) ? 0 : 128;
    __shared__ float Xl[32][128];
    int j0 = blockIdx.x * 32;
    for (int q = threadIdx.x; q < 32 * 128; q += 256)
        Xl[q >> 7][q & 127] = X[(size_t)(j0 + (q >> 7)) * 128 + (q & 127)];
    __syncthreads();
    int c = threadIdx.x & 127;
    int jh = threadIdx.x >> 7;
    float bv = (tbl == 0) ? b_rgb[c] : (tbl == 2) ? b_ir[c] : 0.f;
    float acc[16];
#pragma unroll
    for (int s = 0; s < 16; ++s) acc[s] = bv;
    for (int d4 = 0; d4 < 32; ++d4) {
        float w[4];
#pragma unroll
        for (int u = 0; u < 4; ++u) {
            int d = d4 * 4 + u;
            w[u] = W[(size_t)(d + 128) * 128 + c];
            if (comb) w[u] += W[(size_t)d * 128 + c];
        }
#pragma unroll
        for (int jj = 0; jj < 16; ++jj) {
            const float4 xv = *(const float4*)&Xl[jh * 16 + jj][d4 * 4];
            acc[jj] = fmaf(xv.x, w[0], fmaf(xv.y, w[1], fmaf(xv.z, w[2], fmaf(xv.w, w[3], acc[jj]))));
        }
    }
#pragma unroll
    for (int jj = 0; jj < 16; ++jj)
        out[(size_t)(j0 + jh * 16 + jj) * 256 + off + c] = f2bf(acc[jj]);
}

// ------ 5. cross-quarter merge + pair accumulation (kmerge folded in) -----
__global__ __launch_bounds__(256) void pairsum_kernel(const unsigned* __restrict__ Cand,
                                                      const unsigned short* __restrict__ ABa,
                                                      const unsigned short* __restrict__ ABb,
                                                      float* __restrict__ Spart) {
    __shared__ unsigned cbuf[64][64];   // 64 (mod,query) rows x 4 sorted 16-runs
    __shared__ int ia[512], ib[512];
    __shared__ float red[8][256];
    int chunk = blockIdx.x, n = blockIdx.y;
    int i0 = chunk * 32;
    // stage Cand rows for queries i0..i0+31, both modalities
#pragma unroll
    for (int w = 0; w < 16; ++w) {
        int idx = w * 256 + threadIdx.x;
        int row = idx >> 6, e = idx & 63;
        int mod = row >> 5, qq = i0 + (row & 31);
        cbuf[row][e] = Cand[(((size_t)(2 * n + mod) * 4096) + qq) * 64 + e];
    }
    __syncthreads();
    // 64 threads: 4-way merge of sorted runs -> 16 neighbor indices
    if (threadIdx.x < 64) {
        int t = threadIdx.x;
        int mod = t >> 5, ql = t & 31;
        const unsigned* row = cbuf[t];
        int* dst = mod ? ib : ia;
        int h0 = 0, h1 = 0, h2 = 0, h3 = 0;
#pragma unroll 1
        for (int kk = 0; kk < 16; ++kk) {
            unsigned c0 = row[h0], c1 = row[16 + h1], c2 = row[32 + h2], c3 = row[48 + h3];
            unsigned mm = max(max(c0, c1), max(c2, c3));
            dst[ql * 16 + kk] = (int)(mm & 0xFFFu);
            h0 += (c0 == mm); h1 += (c1 == mm); h2 += (c2 == mm); h3 += (c3 == mm);
        }
    }
    __syncthreads();
    int c4 = threadIdx.x & 31, hw = threadIdx.x >> 5;   // 8 half-waves
    // lanes 0-15: rgb part leaky(A1'[a]-A2[b]); lanes 16-31: ir part leaky(B1'[b]-B2[a])
    float s = (c4 < 16) ? 1.f : -1.f;
    float acc[8];
#pragma unroll
    for (int j = 0; j < 8; ++j) acc[j] = 0.f;
#pragma unroll 4
    for (int q = hw; q < 512; q += 8) {
        int a = ia[q], b = ib[q];
        ushort8 ua = *(const ushort8*)(ABa + (size_t)a * 256 + c4 * 8);
        ushort8 ub = *(const ushort8*)(ABb + (size_t)b * 256 + c4 * 8);
#pragma unroll
        for (int j = 0; j < 8; ++j) {
            float av = __uint_as_float((unsigned)ua[j] << 16);
            float bv = __uint_as_float((unsigned)ub[j] << 16);
            float x = s * (av - bv);
            acc[j] += (x >= 0.f) ? x : NEG * x;
        }
    }
    *(float4*)&red[hw][c4 * 8] = *(float4*)&acc[0];
    *(float4*)&red[hw][c4 * 8 + 4] = *(float4*)&acc[4];
    __syncthreads();
    float ssum = 0.f;
#pragma unroll
    for (int p = 0; p < 8; ++p) ssum += red[p][threadIdx.x];
    Spart[((size_t)n * 128 + chunk) * 256 + threadIdx.x] = ssum;
}

// ------------- 6. SE gate (reduce folded in; 1 block/batch) ---------------
__global__ __launch_bounds__(256) void gate_kernel(const float* __restrict__ Spart,
                                                   const float* __restrict__ se_w1,
                                                   const float* __restrict__ se_b1,
                                                   const float* __restrict__ se_w2,
                                                   const float* __restrict__ se_b2,
                                                   float* __restrict__ gate) {
    int n = blockIdx.x;
    __shared__ float m[256];
    __shared__ float hid[8];
    int d = threadIdx.x;
    float s = 0.f;
#pragma unroll 8
    for (int p = 0; p < 128; ++p)
        s += Spart[((size_t)n * 128 + p) * 256 + d];
    m[d] = s * (1.0f / 65536.0f);
    __syncthreads();
    if (threadIdx.x < 8) {
        float h = se_b1[threadIdx.x];
        for (int dd = 0; dd < 256; ++dd) h += m[dd] * se_w1[dd * 8 + threadIdx.x];
        hid[threadIdx.x] = leaky(h);
    }
    __syncthreads();
    if (threadIdx.x < 128) {
        float z = se_b2[threadIdx.x];
#pragma unroll
        for (int j = 0; j < 8; ++j) z += hid[j] * se_w2[j * 128 + threadIdx.x];
        gate[n * 128 + threadIdx.x] = 1.0f / (1.0f + expf(-z));
    }
}

// -------------------- 7. blend + relu, NCHW output ------------------------
__global__ __launch_bounds__(256) void out_kernel(const float* __restrict__ Pr,
                                                  const float* __restrict__ Pi,
                                                  const float* __restrict__ gate,
                                                  const float* __restrict__ g1p,
                                                  const float* __restrict__ g2p,
                                                  float* __restrict__ out) {
    int q = blockIdx.x * 256 + threadIdx.x;  // float4 idx, 524288 total
    int nc = q >> 10;
    float g = gate[nc];
    float gr = g1p[0] * g, gi = g2p[0] * (1.f - g);
    float4 r = *(const float4*)(Pr + (size_t)q * 4);
    float4 i = *(const float4*)(Pi + (size_t)q * 4);
    float4 o;
    o.x = fmaxf(gr * r.x + gi * i.x, 0.f);
    o.y = fmaxf(gr * r.y + gi * i.y, 0.f);
    o.z = fmaxf(gr * r.z + gi * i.z, 0.f);
    o.w = fmaxf(gr * r.w + gi * i.w, 0.f);
    *(float4*)(out + (size_t)q * 4) = o;
}

extern "C" void kernel_launch(void* const* d_in, const int* in_sizes, int n_in,
                              void* d_out, int out_size, void* d_ws, size_t ws_size,
                              hipStream_t stream) {
    const float* rgb = (const float*)d_in[0];
    const float* ir = (const float*)d_in[1];
    const float* Wr = (const float*)d_in[2];
    const float* br = (const float*)d_in[3];
    const float* Wi = (const float*)d_in[4];
    const float* bi = (const float*)d_in[5];
    const float* sw1 = (const float*)d_in[6];
    const float* sb1 = (const float*)d_in[7];
    const float* sw2 = (const float*)d_in[8];
    const float* sb2 = (const float*)d_in[9];
    const float* g1 = (const float*)d_in[10];
    const float* g2 = (const float*)d_in[11];
    float* out = (float*)d_out;

    char* ws = (char*)d_ws;
    float* Pr = (float*)ws;                     ws += (size_t)8 << 20;
    float* Pi = (float*)ws;                     ws += (size_t)8 << 20;
    unsigned short* xnr = (unsigned short*)ws;  ws += (size_t)4 << 20;
    unsigned short* xni = (unsigned short*)ws;  ws += (size_t)4 << 20;
    float* Pt0r = (float*)ws;                   ws += (size_t)2 << 20;
    float* Pt0i = (float*)ws;                   ws += (size_t)2 << 20;
    unsigned* Cand = (unsigned*)ws;             ws += (size_t)8 << 20;
    unsigned short* ABa = (unsigned short*)ws;  ws += (size_t)2 << 20;
    unsigned short* ABb = (unsigned short*)ws;  ws += (size_t)2 << 20;
    float* Spart = (float*)ws;                  ws += (size_t)512 << 10;
    float* gate = (float*)ws;                   ws += 4096;

    pool_kernel<<<dim3(2048, 2), 256, 0, stream>>>(rgb, ir, Pr, Pi);
    normT_kernel<<<dim3(128, 4, 2), 256, 0, stream>>>(Pr, Pi, Pt0r, Pt0i, xnr, xni);
    knn_kernel<<<dim3(64, 4, 8), 256, 0, stream>>>(xnr, xni, Cand);
    table_kernel<<<dim3(128, 4), 256, 0, stream>>>(Pt0r, Pt0i, Wr, Wi, br, bi, ABa, ABb);
    pairsum_kernel<<<dim3(128, 4), 256, 0, stream>>>(Cand, ABa, ABb, Spart);
    gate_kernel<<<4, 256, 0, stream>>>(Spart, sw1, sb1, sw2, sb2, gate);
    out_kernel<<<2048, 256, 0, stream>>>(Pr, Pi, gate, g1, g2, out);
}

// Round 9
// 187.805 us; speedup vs baseline: 1.1198x; 1.0165x over previous
//
#include <hip/hip_runtime.h>

typedef short short8 __attribute__((ext_vector_type(8)));
typedef unsigned short ushort8 __attribute__((ext_vector_type(8)));
typedef float f32x4 __attribute__((ext_vector_type(4)));

#define NEG 0.01f

static __device__ __forceinline__ float leaky(float x) { return x >= 0.f ? x : NEG * x; }

static __device__ __forceinline__ unsigned short f2bf(float f) {
    unsigned int u = __float_as_uint(f);
    unsigned int r = (u + 0x7fff + ((u >> 16) & 1)) >> 16;
    return (unsigned short)r;
}

// async global->LDS, 16B per lane: LDS dest = wave-uniform base + lane*16
static __device__ __forceinline__ void gload_lds16(const void* g, void* l) {
    __builtin_amdgcn_global_load_lds((const __attribute__((address_space(1))) void*)g,
                                     (__attribute__((address_space(3))) void*)l, 16, 0, 0);
}

// ---- 1. fused maxpool 2x2 + transpose + l2-norm -> bf16 (+Pt0 batch0) ----
// grid (128 hw-tiles of 32, 4 n, 2 mod); 256 thr. Each block: one output row
// half (oh fixed, 32 ow), all 128 c. Writes pooled P (NCHW), normalized bf16
// xn [n][hw][c], and fp32 Pt0 [hw][c] for batch 0.
__global__ __launch_bounds__(256) void prep_kernel(const float* __restrict__ rgb,
                                                   const float* __restrict__ ir,
                                                   float* __restrict__ Pr,
                                                   float* __restrict__ Pi,
                                                   float* __restrict__ Pt0r,
                                                   float* __restrict__ Pt0i,
                                                   unsigned short* __restrict__ xnr,
                                                   unsigned short* __restrict__ xni) {
    const float* src = blockIdx.z ? ir : rgb;
    float* P = blockIdx.z ? Pi : Pr;
    float* Pt0 = blockIdx.z ? Pt0i : Pt0r;
    unsigned short* xn = blockIdx.z ? xni : xnr;
    int n = blockIdx.y;
    int hw0 = blockIdx.x * 32;
    int oh = hw0 >> 6;
    int ow0 = hw0 & 63;
    __shared__ float tile[32][129];
    __shared__ float psum[32][8];
    __shared__ float invn[32];
    int hwl = threadIdx.x & 31;
    int cg = threadIdx.x >> 5;
    int ow = ow0 + hwl;
    float ssq = 0.f;
#pragma unroll
    for (int ii = 0; ii < 16; ++ii) {
        int c = cg * 16 + ii;
        const float* ib = src + ((size_t)(n * 128 + c) * 128 + 2 * oh) * 128 + 2 * ow;
        float2 a = *(const float2*)ib;
        float2 b = *(const float2*)(ib + 128);
        float v = fmaxf(fmaxf(a.x, a.y), fmaxf(b.x, b.y));
        tile[hwl][c] = v;
        ssq += v * v;
        P[(size_t)(n * 128 + c) * 4096 + hw0 + hwl] = v;
    }
    psum[hwl][cg] = ssq;
    __syncthreads();
    if (threadIdx.x < 32) {
        float s = 0.f;
#pragma unroll
        for (int g = 0; g < 8; ++g) s += psum[threadIdx.x][g];
        invn[threadIdx.x] = 1.0f / fmaxf(sqrtf(s), 1e-12f);
    }
    __syncthreads();
    int c = threadIdx.x & 127;
    int rh = threadIdx.x >> 7;
#pragma unroll
    for (int rr = 0; rr < 16; ++rr) {
        int r = rh * 16 + rr;
        float v = tile[r][c];
        xn[((size_t)n * 4096 + hw0 + r) * 128 + c] = f2bf(v * invn[r]);
        if (n == 0) Pt0[(size_t)(hw0 + r) * 128 + c] = v;
    }
}

// ------ 3. fused gram (bf16 MFMA) + sorted top-16, candidate-quartered ----
// grid: (64 row-blocks of 64 queries, 4 cand-quarters, 8 nz); 256 thr.
// Staging via global_load_lds (linear LDS dest, pre-swizzled global source
// col = ch^(r&15); read slot = (kt*4+kg)^frow) -> zero staging VALU ops,
// zero write-side bank conflicts. Double-buffered, 1 barrier/tile
// (__syncthreads drains vmcnt). Per lane: 16 scores/tile packed
// (positive-biased float bits | 12-bit idx), Batcher sort-16 + bitonic merge
// into sorted running top-16; 4 kg-runs merged; top-16/(query,quarter) out.
__global__ __launch_bounds__(256, 4) void knn_kernel(const unsigned short* __restrict__ xnr,
                                                     const unsigned short* __restrict__ xni,
                                                     unsigned* __restrict__ Cand) {
    __shared__ __align__(16) char smem[32768];   // 2 x 16KB tiles; merge buf overlay
    const int nz = blockIdx.z;
    const int n = nz >> 1;
    const unsigned short* xn = (nz & 1) ? xni : xnr;
    const int quarter = blockIdx.y;
    const int r0 = blockIdx.x * 64;
    const int tid = threadIdx.x;
    const int wave = tid >> 6, lane = tid & 63;
    const int frow = lane & 15, kg = lane >> 4;
    const int kg16 = kg * 16;
    const int cand0 = quarter * 1024;

    // per-lane pre-swizzled global source offsets (ushort units)
    int soff[4];
#pragma unroll
    for (int it = 0; it < 4; ++it) {
        int idx = it * 256 + tid;
        int r = idx >> 4, ch = idx & 15;
        soff[it] = r * 128 + ((ch ^ (r & 15)) * 8);
    }

    // B-fragments: this wave's 16 query rows, loaded once
    short8 bq[4];
    {
        const unsigned short* qsrc = xn + ((size_t)n * 4096 + r0 + wave * 16 + frow) * 128;
#pragma unroll
        for (int kt = 0; kt < 4; ++kt)
            bq[kt] = *(const short8*)(qsrc + kt * 32 + kg * 8);
    }

    const unsigned short* tbase = xn + ((size_t)n * 4096 + cand0) * 128;

    // stage tile 0 -> buf0
#pragma unroll
    for (int it = 0; it < 4; ++it)
        gload_lds16(tbase + soff[it], smem + it * 4096 + wave * 1024);
    __syncthreads();

    unsigned val[16];   // running top-16, sorted descending
#pragma unroll
    for (int s = 0; s < 16; ++s) val[s] = 0u;

    for (int t = 0; t < 16; ++t) {
        // issue async loads for tile t+1 into the other buffer (that buffer
        // was last read at iter t-1; the barrier ending t-1 freed it)
        if (t < 15) {
            const unsigned short* src = tbase + (size_t)(t + 1) * 64 * 128;
            char* bn = smem + ((t & 1) ? 0 : 16384);
#pragma unroll
            for (int it = 0; it < 4; ++it)
                gload_lds16(src + soff[it], bn + it * 4096 + wave * 1024);
        }
        const char* bc = smem + ((t & 1) ? 16384 : 0);
        f32x4 acc0 = {2.f, 2.f, 2.f, 2.f}, acc1 = {2.f, 2.f, 2.f, 2.f};
        f32x4 acc2 = {2.f, 2.f, 2.f, 2.f}, acc3 = {2.f, 2.f, 2.f, 2.f};
#pragma unroll
        for (int kt = 0; kt < 4; ++kt) {
            int ko = (kt * 64 + kg16) ^ (frow << 4);
            short8 b = bq[kt];
            short8 a0 = *(const short8*)(bc + (frow)*256 + ko);
            short8 a1 = *(const short8*)(bc + (16 + frow) * 256 + ko);
            short8 a2 = *(const short8*)(bc + (32 + frow) * 256 + ko);
            short8 a3 = *(const short8*)(bc + (48 + frow) * 256 + ko);
            acc0 = __builtin_amdgcn_mfma_f32_16x16x32_bf16(a0, b, acc0, 0, 0, 0);
            acc1 = __builtin_amdgcn_mfma_f32_16x16x32_bf16(a1, b, acc1, 0, 0, 0);
            acc2 = __builtin_amdgcn_mfma_f32_16x16x32_bf16(a2, b, acc2, 0, 0, 0);
            acc3 = __builtin_amdgcn_mfma_f32_16x16x32_bf16(a3, b, acc3, 0, 0, 0);
        }
        // pack: positive-biased score bits (top 20) | candidate idx (12 bits)
        unsigned pk[16];
        const int cb = cand0 + t * 64 + kg * 4;
#define PACK(AC, A_)                                                                        \
    {                                                                                       \
        _Pragma("unroll") for (int j = 0; j < 4; ++j) {                                     \
            pk[A_ * 4 + j] = (__float_as_uint(AC[j]) & 0xFFFFF000u) |                       \
                             (unsigned)(cb + A_ * 16 + j);                                  \
        }                                                                                   \
    }
        PACK(acc0, 0) PACK(acc1, 1) PACK(acc2, 2) PACK(acc3, 3)
#undef PACK

        // Batcher odd-even mergesort, 16 elements, descending (63 CE)
#define CE(i, j)                                          \
    {                                                     \
        unsigned mx = max(pk[i], pk[j]);                  \
        unsigned mn = min(pk[i], pk[j]);                  \
        pk[i] = mx; pk[j] = mn;                           \
    }
        CE(0,1) CE(2,3) CE(4,5) CE(6,7) CE(8,9) CE(10,11) CE(12,13) CE(14,15)
        CE(0,2) CE(1,3) CE(4,6) CE(5,7) CE(8,10) CE(9,11) CE(12,14) CE(13,15)
        CE(1,2) CE(5,6) CE(9,10) CE(13,14)
        CE(0,4) CE(1,5) CE(2,6) CE(3,7) CE(8,12) CE(9,13) CE(10,14) CE(11,15)
        CE(2,4) CE(3,5) CE(10,12) CE(11,13)
        CE(1,2) CE(3,4) CE(5,6) CE(9,10) CE(11,12) CE(13,14)
        CE(0,8) CE(1,9) CE(2,10) CE(3,11) CE(4,12) CE(5,13) CE(6,14) CE(7,15)
        CE(4,8) CE(5,9) CE(6,10) CE(7,11)
        CE(2,4) CE(3,5) CE(6,8) CE(7,9) CE(10,12) CE(11,13)
        CE(1,2) CE(3,4) CE(5,6) CE(7,8) CE(9,10) CE(11,12) CE(13,14)
#undef CE

        // half-cleaner: top-16 of merge(val desc, pk desc) as bitonic seq
#pragma unroll
        for (int i = 0; i < 16; ++i) val[i] = max(val[i], pk[15 - i]);
        // bitonic merge -> descending sorted
#define CEV(i, j)                                         \
    {                                                     \
        unsigned mx = max(val[i], val[j]);                \
        unsigned mn = min(val[i], val[j]);                \
        val[i] = mx; val[j] = mn;                         \
    }
        CEV(0,8) CEV(1,9) CEV(2,10) CEV(3,11) CEV(4,12) CEV(5,13) CEV(6,14) CEV(7,15)
        CEV(0,4) CEV(1,5) CEV(2,6) CEV(3,7) CEV(8,12) CEV(9,13) CEV(10,14) CEV(11,15)
        CEV(0,2) CEV(1,3) CEV(4,6) CEV(5,7) CEV(8,10) CEV(9,11) CEV(12,14) CEV(13,15)
        CEV(0,1) CEV(2,3) CEV(4,5) CEV(6,7) CEV(8,9) CEV(10,11) CEV(12,13) CEV(14,15)
#undef CEV

        __syncthreads();   // drains vmcnt: tile t+1 resident; buffers settled
    }

    // 4 sorted kg-runs per query -> 4-way merge -> sorted top-16 packed out
    {
        unsigned* mbuf = (unsigned*)smem;
        int query = wave * 16 + frow;
#pragma unroll
        for (int s = 0; s < 16; ++s) mbuf[query * 65 + kg16 + s] = val[s];
        __syncthreads();
        if (tid < 64) {
            unsigned* outp = Cand + (((size_t)nz * 4096 + r0 + tid) * 4 + quarter) * 16;
            const unsigned* row = mbuf + tid * 65;
            int h0 = 0, h1 = 0, h2 = 0, h3 = 0;
#pragma unroll 1
            for (int kk = 0; kk < 16; ++kk) {
                unsigned c0 = row[h0], c1 = row[16 + h1], c2 = row[32 + h2], c3 = row[48 + h3];
                unsigned mm = max(max(c0, c1), max(c2, c3));
                outp[kk] = mm;
                h0 += (c0 == mm); h1 += (c1 == mm); h2 += (c2 == mm); h3 += (c3 == mm);
            }
        }
    }
}

// --- 4. fused bf16 node tables with bias folded in -----------------------
// ABa[j] = [ A1'=hr@(W1+W2)+br | B2=hr@V2 ]   (indexed by rgb-knn a)
// ABb[j] = [ A2 =hi@W2         | B1'=hi@(V1+V2)+bi ]   (indexed by ir-knn b)
__global__ __launch_bounds__(256) void table_kernel(const float* __restrict__ Pt0r,
                                                    const float* __restrict__ Pt0i,
                                                    const float* __restrict__ Wr,
                                                    const float* __restrict__ Wi,
                                                    const float* __restrict__ b_rgb,
                                                    const float* __restrict__ b_ir,
                                                    unsigned short* __restrict__ ABa,
                                                    unsigned short* __restrict__ ABb) {
    int tbl = blockIdx.y;
    const float* X = (tbl == 0 || tbl == 3) ? Pt0r : Pt0i;
    const float* W = (tbl <= 1) ? Wr : Wi;
    bool comb = (tbl == 0 || tbl == 2);
    unsigned short* out = (tbl == 0 || tbl == 3) ? ABa : ABb;
    int off = (tbl <= 1) ? 0 : 128;
    __shared__ float Xl[32][128];
    int j0 = blockIdx.x * 32;
    for (int q = threadIdx.x; q < 32 * 128; q += 256)
        Xl[q >> 7][q & 127] = X[(size_t)(j0 + (q >> 7)) * 128 + (q & 127)];
    __syncthreads();
    int c = threadIdx.x & 127;
    int jh = threadIdx.x >> 7;
    float bv = (tbl == 0) ? b_rgb[c] : (tbl == 2) ? b_ir[c] : 0.f;
    float acc[16];
#pragma unroll
    for (int s = 0; s < 16; ++s) acc[s] = bv;
    for (int d4 = 0; d4 < 32; ++d4) {
        float w[4];
#pragma unroll
        for (int u = 0; u < 4; ++u) {
            int d = d4 * 4 + u;
            w[u] = W[(size_t)(d + 128) * 128 + c];
            if (comb) w[u] += W[(size_t)d * 128 + c];
        }
#pragma unroll
        for (int jj = 0; jj < 16; ++jj) {
            const float4 xv = *(const float4*)&Xl[jh * 16 + jj][d4 * 4];
            acc[jj] = fmaf(xv.x, w[0], fmaf(xv.y, w[1], fmaf(xv.z, w[2], fmaf(xv.w, w[3], acc[jj]))));
        }
    }
#pragma unroll
    for (int jj = 0; jj < 16; ++jj)
        out[(size_t)(j0 + jh * 16 + jj) * 256 + off + c] = f2bf(acc[jj]);
}

// ------ 5. cross-quarter merge + pair accumulation (kmerge folded in) -----
__global__ __launch_bounds__(256) void pairsum_kernel(const unsigned* __restrict__ Cand,
                                                      const unsigned short* __restrict__ ABa,
                                                      const unsigned short* __restrict__ ABb,
                                                      float* __restrict__ Spart) {
    __shared__ unsigned cbuf[64][64];   // 64 (mod,query) rows x 4 sorted 16-runs
    __shared__ int ia[512], ib[512];
    __shared__ float red[8][256];
    int chunk = blockIdx.x, n = blockIdx.y;
    int i0 = chunk * 32;
#pragma unroll
    for (int w = 0; w < 16; ++w) {
        int idx = w * 256 + threadIdx.x;
        int row = idx >> 6, e = idx & 63;
        int mod = row >> 5, qq = i0 + (row & 31);
        cbuf[row][e] = Cand[(((size_t)(2 * n + mod) * 4096) + qq) * 64 + e];
    }
    __syncthreads();
    if (threadIdx.x < 64) {
        int t = threadIdx.x;
        int mod = t >> 5, ql = t & 31;
        const unsigned* row = cbuf[t];
        int* dst = mod ? ib : ia;
        int h0 = 0, h1 = 0, h2 = 0, h3 = 0;
#pragma unroll 1
        for (int kk = 0; kk < 16; ++kk) {
            unsigned c0 = row[h0], c1 = row[16 + h1], c2 = row[32 + h2], c3 = row[48 + h3];
            unsigned mm = max(max(c0, c1), max(c2, c3));
            dst[ql * 16 + kk] = (int)(mm & 0xFFFu);
            h0 += (c0 == mm); h1 += (c1 == mm); h2 += (c2 == mm); h3 += (c3 == mm);
        }
    }
    __syncthreads();
    int c4 = threadIdx.x & 31, hw = threadIdx.x >> 5;   // 8 half-waves
    float s = (c4 < 16) ? 1.f : -1.f;
    float acc[8];
#pragma unroll
    for (int j = 0; j < 8; ++j) acc[j] = 0.f;
#pragma unroll 4
    for (int q = hw; q < 512; q += 8) {
        int a = ia[q], b = ib[q];
        ushort8 ua = *(const ushort8*)(ABa + (size_t)a * 256 + c4 * 8);
        ushort8 ub = *(const ushort8*)(ABb + (size_t)b * 256 + c4 * 8);
#pragma unroll
        for (int j = 0; j < 8; ++j) {
            float av = __uint_as_float((unsigned)ua[j] << 16);
            float bv = __uint_as_float((unsigned)ub[j] << 16);
            float x = s * (av - bv);
            acc[j] += (x >= 0.f) ? x : NEG * x;
        }
    }
    *(float4*)&red[hw][c4 * 8] = *(float4*)&acc[0];
    *(float4*)&red[hw][c4 * 8 + 4] = *(float4*)&acc[4];
    __syncthreads();
    float ssum = 0.f;
#pragma unroll
    for (int p = 0; p < 8; ++p) ssum += red[p][threadIdx.x];
    Spart[((size_t)n * 128 + chunk) * 256 + threadIdx.x] = ssum;
}

// ------------- 6. SE gate (reduce folded in; 1 block/batch) ---------------
__global__ __launch_bounds__(256) void gate_kernel(const float* __restrict__ Spart,
                                                   const float* __restrict__ se_w1,
                                                   const float* __restrict__ se_b1,
                                                   const float* __restrict__ se_w2,
                                                   const float* __restrict__ se_b2,
                                                   float* __restrict__ gate) {
    int n = blockIdx.x;
    __shared__ float m[256];
    __shared__ float hid[8];
    int d = threadIdx.x;
    float s = 0.f;
#pragma unroll 8
    for (int p = 0; p < 128; ++p)
        s += Spart[((size_t)n * 128 + p) * 256 + d];
    m[d] = s * (1.0f / 65536.0f);
    __syncthreads();
    if (threadIdx.x < 8) {
        float h = se_b1[threadIdx.x];
        for (int dd = 0; dd < 256; ++dd) h += m[dd] * se_w1[dd * 8 + threadIdx.x];
        hid[threadIdx.x] = leaky(h);
    }
    __syncthreads();
    if (threadIdx.x < 128) {
        float z = se_b2[threadIdx.x];
#pragma unroll
        for (int j = 0; j < 8; ++j) z += hid[j] * se_w2[j * 128 + threadIdx.x];
        gate[n * 128 + threadIdx.x] = 1.0f / (1.0f + expf(-z));
    }
}

// -------------------- 7. blend + relu, NCHW output ------------------------
__global__ __launch_bounds__(256) void out_kernel(const float* __restrict__ Pr,
                                                  const float* __restrict__ Pi,
                                                  const float* __restrict__ gate,
                                                  const float* __restrict__ g1p,
                                                  const float* __restrict__ g2p,
                                                  float* __restrict__ out) {
    int q = blockIdx.x * 256 + threadIdx.x;  // float4 idx, 524288 total
    int nc = q >> 10;
    float g = gate[nc];
    float gr = g1p[0] * g, gi = g2p[0] * (1.f - g);
    float4 r = *(const float4*)(Pr + (size_t)q * 4);
    float4 i = *(const float4*)(Pi + (size_t)q * 4);
    float4 o;
    o.x = fmaxf(gr * r.x + gi * i.x, 0.f);
    o.y = fmaxf(gr * r.y + gi * i.y, 0.f);
    o.z = fmaxf(gr * r.z + gi * i.z, 0.f);
    o.w = fmaxf(gr * r.w + gi * i.w, 0.f);
    *(float4*)(out + (size_t)q * 4) = o;
}

extern "C" void kernel_launch(void* const* d_in, const int* in_sizes, int n_in,
                              void* d_out, int out_size, void* d_ws, size_t ws_size,
                              hipStream_t stream) {
    const float* rgb = (const float*)d_in[0];
    const float* ir = (const float*)d_in[1];
    const float* Wr = (const float*)d_in[2];
    const float* br = (const float*)d_in[3];
    const float* Wi = (const float*)d_in[4];
    const float* bi = (const float*)d_in[5];
    const float* sw1 = (const float*)d_in[6];
    const float* sb1 = (const float*)d_in[7];
    const float* sw2 = (const float*)d_in[8];
    const float* sb2 = (const float*)d_in[9];
    const float* g1 = (const float*)d_in[10];
    const float* g2 = (const float*)d_in[11];
    float* out = (float*)d_out;

    char* ws = (char*)d_ws;
    float* Pr = (float*)ws;                     ws += (size_t)8 << 20;
    float* Pi = (float*)ws;                     ws += (size_t)8 << 20;
    unsigned short* xnr = (unsigned short*)ws;  ws += (size_t)4 << 20;
    unsigned short* xni = (unsigned short*)ws;  ws += (size_t)4 << 20;
    float* Pt0r = (float*)ws;                   ws += (size_t)2 << 20;
    float* Pt0i = (float*)ws;                   ws += (size_t)2 << 20;
    unsigned* Cand = (unsigned*)ws;             ws += (size_t)8 << 20;
    unsigned short* ABa = (unsigned short*)ws;  ws += (size_t)2 << 20;
    unsigned short* ABb = (unsigned short*)ws;  ws += (size_t)2 << 20;
    float* Spart = (float*)ws;                  ws += (size_t)512 << 10;
    float* gate = (float*)ws;                   ws += 4096;

    prep_kernel<<<dim3(128, 4, 2), 256, 0, stream>>>(rgb, ir, Pr, Pi, Pt0r, Pt0i, xnr, xni);
    knn_kernel<<<dim3(64, 4, 8), 256, 0, stream>>>(xnr, xni, Cand);
    table_kernel<<<dim3(128, 4), 256, 0, stream>>>(Pt0r, Pt0i, Wr, Wi, br, bi, ABa, ABb);
    pairsum_kernel<<<dim3(128, 4), 256, 0, stream>>>(Cand, ABa, ABb, Spart);
    gate_kernel<<<4, 256, 0, stream>>>(Spart, sw1, sb1, sw2, sb2, gate);
    out_kernel<<<2048, 256, 0, stream>>>(Pr, Pi, gate, g1, g2, out);
}

// Round 10
// 171.349 us; speedup vs baseline: 1.2273x; 1.0960x over previous
//
#include <hip/hip_runtime.h>

typedef short short8 __attribute__((ext_vector_type(8)));
typedef unsigned short ushort8 __attribute__((ext_vector_type(8)));
typedef float f32x4 __attribute__((ext_vector_type(4)));

#define NEG 0.01f

static __device__ __forceinline__ float leaky(float x) { return x >= 0.f ? x : NEG * x; }

static __device__ __forceinline__ unsigned short f2bf(float f) {
    unsigned int u = __float_as_uint(f);
    unsigned int r = (u + 0x7fff + ((u >> 16) & 1)) >> 16;
    return (unsigned short)r;
}

// async global->LDS, 16B per lane: LDS dest = wave-uniform base + lane*16
static __device__ __forceinline__ void gload_lds16(const void* g, void* l) {
    __builtin_amdgcn_global_load_lds((const __attribute__((address_space(1))) void*)g,
                                     (__attribute__((address_space(3))) void*)l, 16, 0, 0);
}

// ---- 1. fused maxpool 2x2 + transpose + l2-norm -> bf16 (+Pt0 batch0) ----
__global__ __launch_bounds__(256) void prep_kernel(const float* __restrict__ rgb,
                                                   const float* __restrict__ ir,
                                                   float* __restrict__ Pr,
                                                   float* __restrict__ Pi,
                                                   float* __restrict__ Pt0r,
                                                   float* __restrict__ Pt0i,
                                                   unsigned short* __restrict__ xnr,
                                                   unsigned short* __restrict__ xni) {
    const float* src = blockIdx.z ? ir : rgb;
    float* P = blockIdx.z ? Pi : Pr;
    float* Pt0 = blockIdx.z ? Pt0i : Pt0r;
    unsigned short* xn = blockIdx.z ? xni : xnr;
    int n = blockIdx.y;
    int hw0 = blockIdx.x * 32;
    int oh = hw0 >> 6;
    int ow0 = hw0 & 63;
    __shared__ float tile[32][129];
    __shared__ float psum[32][8];
    __shared__ float invn[32];
    int hwl = threadIdx.x & 31;
    int cg = threadIdx.x >> 5;
    int ow = ow0 + hwl;
    float ssq = 0.f;
#pragma unroll
    for (int ii = 0; ii < 16; ++ii) {
        int c = cg * 16 + ii;
        const float* ib = src + ((size_t)(n * 128 + c) * 128 + 2 * oh) * 128 + 2 * ow;
        float2 a = *(const float2*)ib;
        float2 b = *(const float2*)(ib + 128);
        float v = fmaxf(fmaxf(a.x, a.y), fmaxf(b.x, b.y));
        tile[hwl][c] = v;
        ssq += v * v;
        P[(size_t)(n * 128 + c) * 4096 + hw0 + hwl] = v;
    }
    psum[hwl][cg] = ssq;
    __syncthreads();
    if (threadIdx.x < 32) {
        float s = 0.f;
#pragma unroll
        for (int g = 0; g < 8; ++g) s += psum[threadIdx.x][g];
        invn[threadIdx.x] = 1.0f / fmaxf(sqrtf(s), 1e-12f);
    }
    __syncthreads();
    int c = threadIdx.x & 127;
    int rh = threadIdx.x >> 7;
#pragma unroll
    for (int rr = 0; rr < 16; ++rr) {
        int r = rh * 16 + rr;
        float v = tile[r][c];
        xn[((size_t)n * 4096 + hw0 + r) * 128 + c] = f2bf(v * invn[r]);
        if (n == 0) Pt0[(size_t)(hw0 + r) * 128 + c] = v;
    }
}

// --- 3+4 combined dispatch: z<8 -> knn quarter blocks; z>=8 -> table ------
// knn: grid (64 row-blocks of 64 queries, 4 cand-quarters, z=nz); 256 thr;
// staging via global_load_lds (linear LDS dest, pre-swizzled global source
// col = ch^(r&15); read slot = (kt*4+kg)^frow), dbuf, 1 barrier/tile.
// 5 blocks/CU (160KB LDS exactly). Batcher sort-16 + bitonic merge top-16.
// table: ABa[j] = [hr@(W1+W2)+br | hr@V2], ABb[j] = [hi@W2 | hi@(V1+V2)+bi].
__global__ __launch_bounds__(256, 5) void knn_table_kernel(
        const unsigned short* __restrict__ xnr,
        const unsigned short* __restrict__ xni,
        unsigned* __restrict__ Cand,
        const float* __restrict__ Pt0r, const float* __restrict__ Pt0i,
        const float* __restrict__ Wr, const float* __restrict__ Wi,
        const float* __restrict__ b_rgb, const float* __restrict__ b_ir,
        unsigned short* __restrict__ ABa, unsigned short* __restrict__ ABb) {
    __shared__ __align__(16) char smem[32768];

    if (blockIdx.z >= 8) {
        // ---------------- table path ----------------
        int tbl = blockIdx.y;
        const float* X = (tbl == 0 || tbl == 3) ? Pt0r : Pt0i;
        const float* W = (tbl <= 1) ? Wr : Wi;
        bool comb = (tbl == 0 || tbl == 2);
        unsigned short* out = (tbl == 0 || tbl == 3) ? ABa : ABb;
        int off = (tbl <= 1) ? 0 : 128;
        float* Xl = (float*)smem;   // [32][128]
        int j0 = ((int)(blockIdx.z - 8) * 64 + blockIdx.x) * 32;
        for (int q = threadIdx.x; q < 32 * 128; q += 256)
            Xl[q] = X[(size_t)(j0 + (q >> 7)) * 128 + (q & 127)];
        __syncthreads();
        int c = threadIdx.x & 127;
        int jh = threadIdx.x >> 7;
        float bv = (tbl == 0) ? b_rgb[c] : (tbl == 2) ? b_ir[c] : 0.f;
        float acc[16];
#pragma unroll
        for (int s = 0; s < 16; ++s) acc[s] = bv;
        for (int d4 = 0; d4 < 32; ++d4) {
            float w[4];
#pragma unroll
            for (int u = 0; u < 4; ++u) {
                int d = d4 * 4 + u;
                w[u] = W[(size_t)(d + 128) * 128 + c];
                if (comb) w[u] += W[(size_t)d * 128 + c];
            }
#pragma unroll
            for (int jj = 0; jj < 16; ++jj) {
                const float4 xv = *(const float4*)&Xl[(jh * 16 + jj) * 128 + d4 * 4];
                acc[jj] = fmaf(xv.x, w[0], fmaf(xv.y, w[1], fmaf(xv.z, w[2], fmaf(xv.w, w[3], acc[jj]))));
            }
        }
#pragma unroll
        for (int jj = 0; jj < 16; ++jj)
            out[(size_t)(j0 + jh * 16 + jj) * 256 + off + c] = f2bf(acc[jj]);
        return;
    }

    // ---------------- knn path ----------------
    const int nz = blockIdx.z;
    const int n = nz >> 1;
    const unsigned short* xn = (nz & 1) ? xni : xnr;
    const int quarter = blockIdx.y;
    const int r0 = blockIdx.x * 64;
    const int tid = threadIdx.x;
    const int wave = tid >> 6, lane = tid & 63;
    const int frow = lane & 15, kg = lane >> 4;
    const int kg16 = kg * 16;
    const int cand0 = quarter * 1024;

    int soff[4];
#pragma unroll
    for (int it = 0; it < 4; ++it) {
        int idx = it * 256 + tid;
        int r = idx >> 4, ch = idx & 15;
        soff[it] = r * 128 + ((ch ^ (r & 15)) * 8);
    }

    short8 bq[4];
    {
        const unsigned short* qsrc = xn + ((size_t)n * 4096 + r0 + wave * 16 + frow) * 128;
#pragma unroll
        for (int kt = 0; kt < 4; ++kt)
            bq[kt] = *(const short8*)(qsrc + kt * 32 + kg * 8);
    }

    const unsigned short* tbase = xn + ((size_t)n * 4096 + cand0) * 128;

#pragma unroll
    for (int it = 0; it < 4; ++it)
        gload_lds16(tbase + soff[it], smem + it * 4096 + wave * 1024);
    __syncthreads();

    unsigned val[16];
#pragma unroll
    for (int s = 0; s < 16; ++s) val[s] = 0u;

    for (int t = 0; t < 16; ++t) {
        if (t < 15) {
            const unsigned short* src = tbase + (size_t)(t + 1) * 64 * 128;
            char* bn = smem + ((t & 1) ? 0 : 16384);
#pragma unroll
            for (int it = 0; it < 4; ++it)
                gload_lds16(src + soff[it], bn + it * 4096 + wave * 1024);
        }
        const char* bc = smem + ((t & 1) ? 16384 : 0);
        f32x4 acc0 = {2.f, 2.f, 2.f, 2.f}, acc1 = {2.f, 2.f, 2.f, 2.f};
        f32x4 acc2 = {2.f, 2.f, 2.f, 2.f}, acc3 = {2.f, 2.f, 2.f, 2.f};
#pragma unroll
        for (int kt = 0; kt < 4; ++kt) {
            int ko = (kt * 64 + kg16) ^ (frow << 4);
            short8 b = bq[kt];
            short8 a0 = *(const short8*)(bc + (frow)*256 + ko);
            short8 a1 = *(const short8*)(bc + (16 + frow) * 256 + ko);
            short8 a2 = *(const short8*)(bc + (32 + frow) * 256 + ko);
            short8 a3 = *(const short8*)(bc + (48 + frow) * 256 + ko);
            acc0 = __builtin_amdgcn_mfma_f32_16x16x32_bf16(a0, b, acc0, 0, 0, 0);
            acc1 = __builtin_amdgcn_mfma_f32_16x16x32_bf16(a1, b, acc1, 0, 0, 0);
            acc2 = __builtin_amdgcn_mfma_f32_16x16x32_bf16(a2, b, acc2, 0, 0, 0);
            acc3 = __builtin_amdgcn_mfma_f32_16x16x32_bf16(a3, b, acc3, 0, 0, 0);
        }
        unsigned pk[16];
        const int cb = cand0 + t * 64 + kg * 4;
#define PACK(AC, A_)                                                                        \
    {                                                                                       \
        _Pragma("unroll") for (int j = 0; j < 4; ++j) {                                     \
            pk[A_ * 4 + j] = (__float_as_uint(AC[j]) & 0xFFFFF000u) |                       \
                             (unsigned)(cb + A_ * 16 + j);                                  \
        }                                                                                   \
    }
        PACK(acc0, 0) PACK(acc1, 1) PACK(acc2, 2) PACK(acc3, 3)
#undef PACK

#define CE(i, j)                                          \
    {                                                     \
        unsigned mx = max(pk[i], pk[j]);                  \
        unsigned mn = min(pk[i], pk[j]);                  \
        pk[i] = mx; pk[j] = mn;                           \
    }
        CE(0,1) CE(2,3) CE(4,5) CE(6,7) CE(8,9) CE(10,11) CE(12,13) CE(14,15)
        CE(0,2) CE(1,3) CE(4,6) CE(5,7) CE(8,10) CE(9,11) CE(12,14) CE(13,15)
        CE(1,2) CE(5,6) CE(9,10) CE(13,14)
        CE(0,4) CE(1,5) CE(2,6) CE(3,7) CE(8,12) CE(9,13) CE(10,14) CE(11,15)
        CE(2,4) CE(3,5) CE(10,12) CE(11,13)
        CE(1,2) CE(3,4) CE(5,6) CE(9,10) CE(11,12) CE(13,14)
        CE(0,8) CE(1,9) CE(2,10) CE(3,11) CE(4,12) CE(5,13) CE(6,14) CE(7,15)
        CE(4,8) CE(5,9) CE(6,10) CE(7,11)
        CE(2,4) CE(3,5) CE(6,8) CE(7,9) CE(10,12) CE(11,13)
        CE(1,2) CE(3,4) CE(5,6) CE(7,8) CE(9,10) CE(11,12) CE(13,14)
#undef CE

#pragma unroll
        for (int i = 0; i < 16; ++i) val[i] = max(val[i], pk[15 - i]);
#define CEV(i, j)                                         \
    {                                                     \
        unsigned mx = max(val[i], val[j]);                \
        unsigned mn = min(val[i], val[j]);                \
        val[i] = mx; val[j] = mn;                         \
    }
        CEV(0,8) CEV(1,9) CEV(2,10) CEV(3,11) CEV(4,12) CEV(5,13) CEV(6,14) CEV(7,15)
        CEV(0,4) CEV(1,5) CEV(2,6) CEV(3,7) CEV(8,12) CEV(9,13) CEV(10,14) CEV(11,15)
        CEV(0,2) CEV(1,3) CEV(4,6) CEV(5,7) CEV(8,10) CEV(9,11) CEV(12,14) CEV(13,15)
        CEV(0,1) CEV(2,3) CEV(4,5) CEV(6,7) CEV(8,9) CEV(10,11) CEV(12,13) CEV(14,15)
#undef CEV

        __syncthreads();   // drains vmcnt: tile t+1 resident; buffers settled
    }

    {
        unsigned* mbuf = (unsigned*)smem;
        int query = wave * 16 + frow;
#pragma unroll
        for (int s = 0; s < 16; ++s) mbuf[query * 65 + kg16 + s] = val[s];
        __syncthreads();
        if (tid < 64) {
            unsigned* outp = Cand + (((size_t)nz * 4096 + r0 + tid) * 4 + quarter) * 16;
            const unsigned* row = mbuf + tid * 65;
            int h0 = 0, h1 = 0, h2 = 0, h3 = 0;
#pragma unroll 1
            for (int kk = 0; kk < 16; ++kk) {
                unsigned c0 = row[h0], c1 = row[16 + h1], c2 = row[32 + h2], c3 = row[48 + h3];
                unsigned mm = max(max(c0, c1), max(c2, c3));
                outp[kk] = mm;
                h0 += (c0 == mm); h1 += (c1 == mm); h2 += (c2 == mm); h3 += (c3 == mm);
            }
        }
    }
}

// ------ 5. cross-quarter merge + pair accumulation -------------------------
__global__ __launch_bounds__(256) void pairsum_kernel(const unsigned* __restrict__ Cand,
                                                      const unsigned short* __restrict__ ABa,
                                                      const unsigned short* __restrict__ ABb,
                                                      float* __restrict__ Spart) {
    __shared__ unsigned cbuf[64][64];
    __shared__ int ia[512], ib[512];
    __shared__ float red[8][256];
    int chunk = blockIdx.x, n = blockIdx.y;
    int i0 = chunk * 32;
#pragma unroll
    for (int w = 0; w < 16; ++w) {
        int idx = w * 256 + threadIdx.x;
        int row = idx >> 6, e = idx & 63;
        int mod = row >> 5, qq = i0 + (row & 31);
        cbuf[row][e] = Cand[(((size_t)(2 * n + mod) * 4096) + qq) * 64 + e];
    }
    __syncthreads();
    if (threadIdx.x < 64) {
        int t = threadIdx.x;
        int mod = t >> 5, ql = t & 31;
        const unsigned* row = cbuf[t];
        int* dst = mod ? ib : ia;
        int h0 = 0, h1 = 0, h2 = 0, h3 = 0;
#pragma unroll 1
        for (int kk = 0; kk < 16; ++kk) {
            unsigned c0 = row[h0], c1 = row[16 + h1], c2 = row[32 + h2], c3 = row[48 + h3];
            unsigned mm = max(max(c0, c1), max(c2, c3));
            dst[ql * 16 + kk] = (int)(mm & 0xFFFu);
            h0 += (c0 == mm); h1 += (c1 == mm); h2 += (c2 == mm); h3 += (c3 == mm);
        }
    }
    __syncthreads();
    int c4 = threadIdx.x & 31, hw = threadIdx.x >> 5;
    float s = (c4 < 16) ? 1.f : -1.f;
    float acc[8];
#pragma unroll
    for (int j = 0; j < 8; ++j) acc[j] = 0.f;
#pragma unroll 4
    for (int q = hw; q < 512; q += 8) {
        int a = ia[q], b = ib[q];
        ushort8 ua = *(const ushort8*)(ABa + (size_t)a * 256 + c4 * 8);
        ushort8 ub = *(const ushort8*)(ABb + (size_t)b * 256 + c4 * 8);
#pragma unroll
        for (int j = 0; j < 8; ++j) {
            float av = __uint_as_float((unsigned)ua[j] << 16);
            float bv = __uint_as_float((unsigned)ub[j] << 16);
            float x = s * (av - bv);
            acc[j] += (x >= 0.f) ? x : NEG * x;
        }
    }
    *(float4*)&red[hw][c4 * 8] = *(float4*)&acc[0];
    *(float4*)&red[hw][c4 * 8 + 4] = *(float4*)&acc[4];
    __syncthreads();
    float ssum = 0.f;
#pragma unroll
    for (int p = 0; p < 8; ++p) ssum += red[p][threadIdx.x];
    Spart[((size_t)n * 128 + chunk) * 256 + threadIdx.x] = ssum;
}

// ------------- 6. SE gate (512 thr, 2-way split reduction) ----------------
__global__ __launch_bounds__(512) void gate_kernel(const float* __restrict__ Spart,
                                                   const float* __restrict__ se_w1,
                                                   const float* __restrict__ se_b1,
                                                   const float* __restrict__ se_w2,
                                                   const float* __restrict__ se_b2,
                                                   float* __restrict__ gate) {
    int n = blockIdx.x;
    __shared__ float par[512];
    __shared__ float m[256];
    __shared__ float hid[8];
    int d = threadIdx.x & 255, ph = threadIdx.x >> 8;
    float s = 0.f;
#pragma unroll 8
    for (int p = ph; p < 128; p += 2)
        s += Spart[((size_t)n * 128 + p) * 256 + d];
    par[threadIdx.x] = s;
    __syncthreads();
    if (threadIdx.x < 256)
        m[threadIdx.x] = (par[threadIdx.x] + par[threadIdx.x + 256]) * (1.0f / 65536.0f);
    __syncthreads();
    if (threadIdx.x < 8) {
        float h = se_b1[threadIdx.x];
        for (int dd = 0; dd < 256; ++dd) h += m[dd] * se_w1[dd * 8 + threadIdx.x];
        hid[threadIdx.x] = leaky(h);
    }
    __syncthreads();
    if (threadIdx.x < 128) {
        float z = se_b2[threadIdx.x];
#pragma unroll
        for (int j = 0; j < 8; ++j) z += hid[j] * se_w2[j * 128 + threadIdx.x];
        gate[n * 128 + threadIdx.x] = 1.0f / (1.0f + expf(-z));
    }
}

// -------------------- 7. blend + relu, NCHW output ------------------------
__global__ __launch_bounds__(256) void out_kernel(const float* __restrict__ Pr,
                                                  const float* __restrict__ Pi,
                                                  const float* __restrict__ gate,
                                                  const float* __restrict__ g1p,
                                                  const float* __restrict__ g2p,
                                                  float* __restrict__ out) {
    int q = blockIdx.x * 256 + threadIdx.x;
    int nc = q >> 10;
    float g = gate[nc];
    float gr = g1p[0] * g, gi = g2p[0] * (1.f - g);
    float4 r = *(const float4*)(Pr + (size_t)q * 4);
    float4 i = *(const float4*)(Pi + (size_t)q * 4);
    float4 o;
    o.x = fmaxf(gr * r.x + gi * i.x, 0.f);
    o.y = fmaxf(gr * r.y + gi * i.y, 0.f);
    o.z = fmaxf(gr * r.z + gi * i.z, 0.f);
    o.w = fmaxf(gr * r.w + gi * i.w, 0.f);
    *(float4*)(out + (size_t)q * 4) = o;
}

extern "C" void kernel_launch(void* const* d_in, const int* in_sizes, int n_in,
                              void* d_out, int out_size, void* d_ws, size_t ws_size,
                              hipStream_t stream) {
    const float* rgb = (const float*)d_in[0];
    const float* ir = (const float*)d_in[1];
    const float* Wr = (const float*)d_in[2];
    const float* br = (const float*)d_in[3];
    const float* Wi = (const float*)d_in[4];
    const float* bi = (const float*)d_in[5];
    const float* sw1 = (const float*)d_in[6];
    const float* sb1 = (const float*)d_in[7];
    const float* sw2 = (const float*)d_in[8];
    const float* sb2 = (const float*)d_in[9];
    const float* g1 = (const float*)d_in[10];
    const float* g2 = (const float*)d_in[11];
    float* out = (float*)d_out;

    char* ws = (char*)d_ws;
    float* Pr = (float*)ws;                     ws += (size_t)8 << 20;
    float* Pi = (float*)ws;                     ws += (size_t)8 << 20;
    unsigned short* xnr = (unsigned short*)ws;  ws += (size_t)4 << 20;
    unsigned short* xni = (unsigned short*)ws;  ws += (size_t)4 << 20;
    float* Pt0r = (float*)ws;                   ws += (size_t)2 << 20;
    float* Pt0i = (float*)ws;                   ws += (size_t)2 << 20;
    unsigned* Cand = (unsigned*)ws;             ws += (size_t)8 << 20;
    unsigned short* ABa = (unsigned short*)ws;  ws += (size_t)2 << 20;
    unsigned short* ABb = (unsigned short*)ws;  ws += (size_t)2 << 20;
    float* Spart = (float*)ws;                  ws += (size_t)512 << 10;
    float* gate = (float*)ws;                   ws += 4096;

    prep_kernel<<<dim3(128, 4, 2), 256, 0, stream>>>(rgb, ir, Pr, Pi, Pt0r, Pt0i, xnr, xni);
    knn_table_kernel<<<dim3(64, 4, 10), 256, 0, stream>>>(xnr, xni, Cand, Pt0r, Pt0i,
                                                          Wr, Wi, br, bi, ABa, ABb);
    pairsum_kernel<<<dim3(128, 4), 256, 0, stream>>>(Cand, ABa, ABb, Spart);
    gate_kernel<<<4, 512, 0, stream>>>(Spart, sw1, sb1, sw2, sb2, gate);
    out_kernel<<<2048, 256, 0, stream>>>(Pr, Pi, gate, g1, g2, out);
}

// Round 11
// 146.721 us; speedup vs baseline: 1.4333x; 1.1679x over previous
//
#include <hip/hip_runtime.h>

typedef short short8 __attribute__((ext_vector_type(8)));
typedef unsigned short ushort8 __attribute__((ext_vector_type(8)));
typedef float f32x4 __attribute__((ext_vector_type(4)));

#define NEG 0.01f

static __device__ __forceinline__ float leaky(float x) { return x >= 0.f ? x : NEG * x; }

static __device__ __forceinline__ unsigned short f2bf(float f) {
    unsigned int u = __float_as_uint(f);
    unsigned int r = (u + 0x7fff + ((u >> 16) & 1)) >> 16;
    return (unsigned short)r;
}

// async global->LDS, 16B per lane: LDS dest = wave-uniform base + lane*16
static __device__ __forceinline__ void gload_lds16(const void* g, void* l) {
    __builtin_amdgcn_global_load_lds((const __attribute__((address_space(1))) void*)g,
                                     (__attribute__((address_space(3))) void*)l, 16, 0, 0);
}

// ---- 1. fused maxpool 2x2 + transpose + l2-norm -> bf16 (+Pt0 batch0) ----
__global__ __launch_bounds__(256) void prep_kernel(const float* __restrict__ rgb,
                                                   const float* __restrict__ ir,
                                                   float* __restrict__ Pr,
                                                   float* __restrict__ Pi,
                                                   float* __restrict__ Pt0r,
                                                   float* __restrict__ Pt0i,
                                                   unsigned short* __restrict__ xnr,
                                                   unsigned short* __restrict__ xni) {
    const float* src = blockIdx.z ? ir : rgb;
    float* P = blockIdx.z ? Pi : Pr;
    float* Pt0 = blockIdx.z ? Pt0i : Pt0r;
    unsigned short* xn = blockIdx.z ? xni : xnr;
    int n = blockIdx.y;
    int hw0 = blockIdx.x * 32;
    int oh = hw0 >> 6;
    int ow0 = hw0 & 63;
    __shared__ float tile[32][129];
    __shared__ float psum[32][8];
    __shared__ float invn[32];
    int hwl = threadIdx.x & 31;
    int cg = threadIdx.x >> 5;
    int ow = ow0 + hwl;
    float ssq = 0.f;
#pragma unroll
    for (int ii = 0; ii < 16; ++ii) {
        int c = cg * 16 + ii;
        const float* ib = src + ((size_t)(n * 128 + c) * 128 + 2 * oh) * 128 + 2 * ow;
        float2 a = *(const float2*)ib;
        float2 b = *(const float2*)(ib + 128);
        float v = fmaxf(fmaxf(a.x, a.y), fmaxf(b.x, b.y));
        tile[hwl][c] = v;
        ssq += v * v;
        P[(size_t)(n * 128 + c) * 4096 + hw0 + hwl] = v;
    }
    psum[hwl][cg] = ssq;
    __syncthreads();
    if (threadIdx.x < 32) {
        float s = 0.f;
#pragma unroll
        for (int g = 0; g < 8; ++g) s += psum[threadIdx.x][g];
        invn[threadIdx.x] = 1.0f / fmaxf(sqrtf(s), 1e-12f);
    }
    __syncthreads();
    int c = threadIdx.x & 127;
    int rh = threadIdx.x >> 7;
#pragma unroll
    for (int rr = 0; rr < 16; ++rr) {
        int r = rh * 16 + rr;
        float v = tile[r][c];
        xn[((size_t)n * 4096 + hw0 + r) * 128 + c] = f2bf(v * invn[r]);
        if (n == 0) Pt0[(size_t)(hw0 + r) * 128 + c] = v;
    }
}

// --- 3+4 combined dispatch: z<2 -> table blocks (short, run first);
//     z>=2 -> knn quarter blocks (nz = z-2). knn: __launch_bounds__(256,4)
// exactly as the R9-verified 85us config. Staging via global_load_lds
// (linear LDS dest, pre-swizzled global col = ch^(r&15); read slot =
// (kt*4+kg)^frow), dbuf, 1 barrier/tile. Batcher sort-16 + bitonic merge.
// table: ABa[j] = [hr@(W1+W2)+br | hr@V2], ABb[j] = [hi@W2 | hi@(V1+V2)+bi].
__global__ __launch_bounds__(256, 4) void knn_table_kernel(
        const unsigned short* __restrict__ xnr,
        const unsigned short* __restrict__ xni,
        unsigned* __restrict__ Cand,
        const float* __restrict__ Pt0r, const float* __restrict__ Pt0i,
        const float* __restrict__ Wr, const float* __restrict__ Wi,
        const float* __restrict__ b_rgb, const float* __restrict__ b_ir,
        unsigned short* __restrict__ ABa, unsigned short* __restrict__ ABb) {
    __shared__ __align__(16) char smem[32768];

    if (blockIdx.z < 2) {
        // ---------------- table path ----------------
        int tbl = blockIdx.y;
        const float* X = (tbl == 0 || tbl == 3) ? Pt0r : Pt0i;
        const float* W = (tbl <= 1) ? Wr : Wi;
        bool comb = (tbl == 0 || tbl == 2);
        unsigned short* out = (tbl == 0 || tbl == 3) ? ABa : ABb;
        int off = (tbl <= 1) ? 0 : 128;
        float* Xl = (float*)smem;   // [32][128]
        int j0 = ((int)blockIdx.z * 64 + blockIdx.x) * 32;
        for (int q = threadIdx.x; q < 32 * 128; q += 256)
            Xl[q] = X[(size_t)(j0 + (q >> 7)) * 128 + (q & 127)];
        __syncthreads();
        int c = threadIdx.x & 127;
        int jh = threadIdx.x >> 7;
        float bv = (tbl == 0) ? b_rgb[c] : (tbl == 2) ? b_ir[c] : 0.f;
        float acc[16];
#pragma unroll
        for (int s = 0; s < 16; ++s) acc[s] = bv;
        for (int d4 = 0; d4 < 32; ++d4) {
            float w[4];
#pragma unroll
            for (int u = 0; u < 4; ++u) {
                int d = d4 * 4 + u;
                w[u] = W[(size_t)(d + 128) * 128 + c];
                if (comb) w[u] += W[(size_t)d * 128 + c];
            }
#pragma unroll
            for (int jj = 0; jj < 16; ++jj) {
                const float4 xv = *(const float4*)&Xl[(jh * 16 + jj) * 128 + d4 * 4];
                acc[jj] = fmaf(xv.x, w[0], fmaf(xv.y, w[1], fmaf(xv.z, w[2], fmaf(xv.w, w[3], acc[jj]))));
            }
        }
#pragma unroll
        for (int jj = 0; jj < 16; ++jj)
            out[(size_t)(j0 + jh * 16 + jj) * 256 + off + c] = f2bf(acc[jj]);
        return;
    }

    // ---------------- knn path ----------------
    const int nz = blockIdx.z - 2;
    const int n = nz >> 1;
    const unsigned short* xn = (nz & 1) ? xni : xnr;
    const int quarter = blockIdx.y;
    const int r0 = blockIdx.x * 64;
    const int tid = threadIdx.x;
    const int wave = tid >> 6, lane = tid & 63;
    const int frow = lane & 15, kg = lane >> 4;
    const int kg16 = kg * 16;
    const int cand0 = quarter * 1024;

    int soff[4];
#pragma unroll
    for (int it = 0; it < 4; ++it) {
        int idx = it * 256 + tid;
        int r = idx >> 4, ch = idx & 15;
        soff[it] = r * 128 + ((ch ^ (r & 15)) * 8);
    }

    short8 bq[4];
    {
        const unsigned short* qsrc = xn + ((size_t)n * 4096 + r0 + wave * 16 + frow) * 128;
#pragma unroll
        for (int kt = 0; kt < 4; ++kt)
            bq[kt] = *(const short8*)(qsrc + kt * 32 + kg * 8);
    }

    const unsigned short* tbase = xn + ((size_t)n * 4096 + cand0) * 128;

#pragma unroll
    for (int it = 0; it < 4; ++it)
        gload_lds16(tbase + soff[it], smem + it * 4096 + wave * 1024);
    __syncthreads();

    unsigned val[16];
#pragma unroll
    for (int s = 0; s < 16; ++s) val[s] = 0u;

    for (int t = 0; t < 16; ++t) {
        if (t < 15) {
            const unsigned short* src = tbase + (size_t)(t + 1) * 64 * 128;
            char* bn = smem + ((t & 1) ? 0 : 16384);
#pragma unroll
            for (int it = 0; it < 4; ++it)
                gload_lds16(src + soff[it], bn + it * 4096 + wave * 1024);
        }
        const char* bc = smem + ((t & 1) ? 16384 : 0);
        f32x4 acc0 = {2.f, 2.f, 2.f, 2.f}, acc1 = {2.f, 2.f, 2.f, 2.f};
        f32x4 acc2 = {2.f, 2.f, 2.f, 2.f}, acc3 = {2.f, 2.f, 2.f, 2.f};
#pragma unroll
        for (int kt = 0; kt < 4; ++kt) {
            int ko = (kt * 64 + kg16) ^ (frow << 4);
            short8 b = bq[kt];
            short8 a0 = *(const short8*)(bc + (frow)*256 + ko);
            short8 a1 = *(const short8*)(bc + (16 + frow) * 256 + ko);
            short8 a2 = *(const short8*)(bc + (32 + frow) * 256 + ko);
            short8 a3 = *(const short8*)(bc + (48 + frow) * 256 + ko);
            acc0 = __builtin_amdgcn_mfma_f32_16x16x32_bf16(a0, b, acc0, 0, 0, 0);
            acc1 = __builtin_amdgcn_mfma_f32_16x16x32_bf16(a1, b, acc1, 0, 0, 0);
            acc2 = __builtin_amdgcn_mfma_f32_16x16x32_bf16(a2, b, acc2, 0, 0, 0);
            acc3 = __builtin_amdgcn_mfma_f32_16x16x32_bf16(a3, b, acc3, 0, 0, 0);
        }
        unsigned pk[16];
        const int cb = cand0 + t * 64 + kg * 4;
#define PACK(AC, A_)                                                                        \
    {                                                                                       \
        _Pragma("unroll") for (int j = 0; j < 4; ++j) {                                     \
            pk[A_ * 4 + j] = (__float_as_uint(AC[j]) & 0xFFFFF000u) |                       \
                             (unsigned)(cb + A_ * 16 + j);                                  \
        }                                                                                   \
    }
        PACK(acc0, 0) PACK(acc1, 1) PACK(acc2, 2) PACK(acc3, 3)
#undef PACK

#define CE(i, j)                                          \
    {                                                     \
        unsigned mx = max(pk[i], pk[j]);                  \
        unsigned mn = min(pk[i], pk[j]);                  \
        pk[i] = mx; pk[j] = mn;                           \
    }
        CE(0,1) CE(2,3) CE(4,5) CE(6,7) CE(8,9) CE(10,11) CE(12,13) CE(14,15)
        CE(0,2) CE(1,3) CE(4,6) CE(5,7) CE(8,10) CE(9,11) CE(12,14) CE(13,15)
        CE(1,2) CE(5,6) CE(9,10) CE(13,14)
        CE(0,4) CE(1,5) CE(2,6) CE(3,7) CE(8,12) CE(9,13) CE(10,14) CE(11,15)
        CE(2,4) CE(3,5) CE(10,12) CE(11,13)
        CE(1,2) CE(3,4) CE(5,6) CE(9,10) CE(11,12) CE(13,14)
        CE(0,8) CE(1,9) CE(2,10) CE(3,11) CE(4,12) CE(5,13) CE(6,14) CE(7,15)
        CE(4,8) CE(5,9) CE(6,10) CE(7,11)
        CE(2,4) CE(3,5) CE(6,8) CE(7,9) CE(10,12) CE(11,13)
        CE(1,2) CE(3,4) CE(5,6) CE(7,8) CE(9,10) CE(11,12) CE(13,14)
#undef CE

#pragma unroll
        for (int i = 0; i < 16; ++i) val[i] = max(val[i], pk[15 - i]);
#define CEV(i, j)                                         \
    {                                                     \
        unsigned mx = max(val[i], val[j]);                \
        unsigned mn = min(val[i], val[j]);                \
        val[i] = mx; val[j] = mn;                         \
    }
        CEV(0,8) CEV(1,9) CEV(2,10) CEV(3,11) CEV(4,12) CEV(5,13) CEV(6,14) CEV(7,15)
        CEV(0,4) CEV(1,5) CEV(2,6) CEV(3,7) CEV(8,12) CEV(9,13) CEV(10,14) CEV(11,15)
        CEV(0,2) CEV(1,3) CEV(4,6) CEV(5,7) CEV(8,10) CEV(9,11) CEV(12,14) CEV(13,15)
        CEV(0,1) CEV(2,3) CEV(4,5) CEV(6,7) CEV(8,9) CEV(10,11) CEV(12,13) CEV(14,15)
#undef CEV

        __syncthreads();   // drains vmcnt: tile t+1 resident; buffers settled
    }

    {
        unsigned* mbuf = (unsigned*)smem;
        int query = wave * 16 + frow;
#pragma unroll
        for (int s = 0; s < 16; ++s) mbuf[query * 65 + kg16 + s] = val[s];
        __syncthreads();
        if (tid < 64) {
            unsigned* outp = Cand + (((size_t)nz * 4096 + r0 + tid) * 4 + quarter) * 16;
            const unsigned* row = mbuf + tid * 65;
            int h0 = 0, h1 = 0, h2 = 0, h3 = 0;
#pragma unroll 1
            for (int kk = 0; kk < 16; ++kk) {
                unsigned c0 = row[h0], c1 = row[16 + h1], c2 = row[32 + h2], c3 = row[48 + h3];
                unsigned mm = max(max(c0, c1), max(c2, c3));
                outp[kk] = mm;
                h0 += (c0 == mm); h1 += (c1 == mm); h2 += (c2 == mm); h3 += (c3 == mm);
            }
        }
    }
}

// ------ 5. cross-quarter merge + pair accumulation -------------------------
__global__ __launch_bounds__(256) void pairsum_kernel(const unsigned* __restrict__ Cand,
                                                      const unsigned short* __restrict__ ABa,
                                                      const unsigned short* __restrict__ ABb,
                                                      float* __restrict__ Spart) {
    __shared__ unsigned cbuf[64][64];
    __shared__ int ia[512], ib[512];
    __shared__ float red[8][256];
    int chunk = blockIdx.x, n = blockIdx.y;
    int i0 = chunk * 32;
#pragma unroll
    for (int w = 0; w < 16; ++w) {
        int idx = w * 256 + threadIdx.x;
        int row = idx >> 6, e = idx & 63;
        int mod = row >> 5, qq = i0 + (row & 31);
        cbuf[row][e] = Cand[(((size_t)(2 * n + mod) * 4096) + qq) * 64 + e];
    }
    __syncthreads();
    if (threadIdx.x < 64) {
        int t = threadIdx.x;
        int mod = t >> 5, ql = t & 31;
        const unsigned* row = cbuf[t];
        int* dst = mod ? ib : ia;
        int h0 = 0, h1 = 0, h2 = 0, h3 = 0;
#pragma unroll 1
        for (int kk = 0; kk < 16; ++kk) {
            unsigned c0 = row[h0], c1 = row[16 + h1], c2 = row[32 + h2], c3 = row[48 + h3];
            unsigned mm = max(max(c0, c1), max(c2, c3));
            dst[ql * 16 + kk] = (int)(mm & 0xFFFu);
            h0 += (c0 == mm); h1 += (c1 == mm); h2 += (c2 == mm); h3 += (c3 == mm);
        }
    }
    __syncthreads();
    int c4 = threadIdx.x & 31, hw = threadIdx.x >> 5;
    float s = (c4 < 16) ? 1.f : -1.f;
    float acc[8];
#pragma unroll
    for (int j = 0; j < 8; ++j) acc[j] = 0.f;
#pragma unroll 4
    for (int q = hw; q < 512; q += 8) {
        int a = ia[q], b = ib[q];
        ushort8 ua = *(const ushort8*)(ABa + (size_t)a * 256 + c4 * 8);
        ushort8 ub = *(const ushort8*)(ABb + (size_t)b * 256 + c4 * 8);
#pragma unroll
        for (int j = 0; j < 8; ++j) {
            float av = __uint_as_float((unsigned)ua[j] << 16);
            float bv = __uint_as_float((unsigned)ub[j] << 16);
            float x = s * (av - bv);
            acc[j] += (x >= 0.f) ? x : NEG * x;
        }
    }
    *(float4*)&red[hw][c4 * 8] = *(float4*)&acc[0];
    *(float4*)&red[hw][c4 * 8 + 4] = *(float4*)&acc[4];
    __syncthreads();
    float ssum = 0.f;
#pragma unroll
    for (int p = 0; p < 8; ++p) ssum += red[p][threadIdx.x];
    Spart[((size_t)n * 128 + chunk) * 256 + threadIdx.x] = ssum;
}

// ------------- 6. SE gate (512 thr, 2-way split reduction) ----------------
__global__ __launch_bounds__(512) void gate_kernel(const float* __restrict__ Spart,
                                                   const float* __restrict__ se_w1,
                                                   const float* __restrict__ se_b1,
                                                   const float* __restrict__ se_w2,
                                                   const float* __restrict__ se_b2,
                                                   float* __restrict__ gate) {
    int n = blockIdx.x;
    __shared__ float par[512];
    __shared__ float m[256];
    __shared__ float hid[8];
    int d = threadIdx.x & 255, ph = threadIdx.x >> 8;
    float s = 0.f;
#pragma unroll 8
    for (int p = ph; p < 128; p += 2)
        s += Spart[((size_t)n * 128 + p) * 256 + d];
    par[threadIdx.x] = s;
    __syncthreads();
    if (threadIdx.x < 256)
        m[threadIdx.x] = (par[threadIdx.x] + par[threadIdx.x + 256]) * (1.0f / 65536.0f);
    __syncthreads();
    if (threadIdx.x < 8) {
        float h = se_b1[threadIdx.x];
        for (int dd = 0; dd < 256; ++dd) h += m[dd] * se_w1[dd * 8 + threadIdx.x];
        hid[threadIdx.x] = leaky(h);
    }
    __syncthreads();
    if (threadIdx.x < 128) {
        float z = se_b2[threadIdx.x];
#pragma unroll
        for (int j = 0; j < 8; ++j) z += hid[j] * se_w2[j * 128 + threadIdx.x];
        gate[n * 128 + threadIdx.x] = 1.0f / (1.0f + expf(-z));
    }
}

// -------------------- 7. blend + relu, NCHW output ------------------------
__global__ __launch_bounds__(256) void out_kernel(const float* __restrict__ Pr,
                                                  const float* __restrict__ Pi,
                                                  const float* __restrict__ gate,
                                                  const float* __restrict__ g1p,
                                                  const float* __restrict__ g2p,
                                                  float* __restrict__ out) {
    int q = blockIdx.x * 256 + threadIdx.x;
    int nc = q >> 10;
    float g = gate[nc];
    float gr = g1p[0] * g, gi = g2p[0] * (1.f - g);
    float4 r = *(const float4*)(Pr + (size_t)q * 4);
    float4 i = *(const float4*)(Pi + (size_t)q * 4);
    float4 o;
    o.x = fmaxf(gr * r.x + gi * i.x, 0.f);
    o.y = fmaxf(gr * r.y + gi * i.y, 0.f);
    o.z = fmaxf(gr * r.z + gi * i.z, 0.f);
    o.w = fmaxf(gr * r.w + gi * i.w, 0.f);
    *(float4*)(out + (size_t)q * 4) = o;
}

extern "C" void kernel_launch(void* const* d_in, const int* in_sizes, int n_in,
                              void* d_out, int out_size, void* d_ws, size_t ws_size,
                              hipStream_t stream) {
    const float* rgb = (const float*)d_in[0];
    const float* ir = (const float*)d_in[1];
    const float* Wr = (const float*)d_in[2];
    const float* br = (const float*)d_in[3];
    const float* Wi = (const float*)d_in[4];
    const float* bi = (const float*)d_in[5];
    const float* sw1 = (const float*)d_in[6];
    const float* sb1 = (const float*)d_in[7];
    const float* sw2 = (const float*)d_in[8];
    const float* sb2 = (const float*)d_in[9];
    const float* g1 = (const float*)d_in[10];
    const float* g2 = (const float*)d_in[11];
    float* out = (float*)d_out;

    char* ws = (char*)d_ws;
    float* Pr = (float*)ws;                     ws += (size_t)8 << 20;
    float* Pi = (float*)ws;                     ws += (size_t)8 << 20;
    unsigned short* xnr = (unsigned short*)ws;  ws += (size_t)4 << 20;
    unsigned short* xni = (unsigned short*)ws;  ws += (size_t)4 << 20;
    float* Pt0r = (float*)ws;                   ws += (size_t)2 << 20;
    float* Pt0i = (float*)ws;                   ws += (size_t)2 << 20;
    unsigned* Cand = (unsigned*)ws;             ws += (size_t)8 << 20;
    unsigned short* ABa = (unsigned short*)ws;  ws += (size_t)2 << 20;
    unsigned short* ABb = (unsigned short*)ws;  ws += (size_t)2 << 20;
    float* Spart = (float*)ws;                  ws += (size_t)512 << 10;
    float* gate = (float*)ws;                   ws += 4096;

    prep_kernel<<<dim3(128, 4, 2), 256, 0, stream>>>(rgb, ir, Pr, Pi, Pt0r, Pt0i, xnr, xni);
    knn_table_kernel<<<dim3(64, 4, 10), 256, 0, stream>>>(xnr, xni, Cand, Pt0r, Pt0i,
                                                          Wr, Wi, br, bi, ABa, ABb);
    pairsum_kernel<<<dim3(128, 4), 256, 0, stream>>>(Cand, ABa, ABb, Spart);
    gate_kernel<<<4, 512, 0, stream>>>(Spart, sw1, sb1, sw2, sb2, gate);
    out_kernel<<<2048, 256, 0, stream>>>(Pr, Pi, gate, g1, g2, out);
}